// Round 9
// baseline (5200.126 us; speedup 1.0000x reference)
//
#include <hip/hip_runtime.h>

#define N_USERS 100000
#define N_ITEMS 200000
#define N_NODES (N_USERS + N_ITEMS)
#define EMB     64
#define NNZ     4000000

// row-buckets: 512 rows each -> fp32 LDS accumulator tile = 512*64*4 = 128KB
#define BSHIFT 9
#define BROWS  (1 << BSHIFT)                               // 512 rows / bucket
#define NBUCK  ((N_NODES + BROWS - 1) >> BSHIFT)           // 586
#define NB2    1024                                        // padded scan slots

// block-aggregated binning pass
#define AGG_THR    512
#define AGG_EPT    8
#define AGG_T      (AGG_THR * AGG_EPT)                     // 4096 edges / block
#define AGG_BLOCKS ((NNZ + AGG_T - 1) / AGG_T)             // 977

// bucket segment capacity (mean fill 6826, sigma ~83 -> +16.5 sigma headroom)
#define SEGCAP 8192

#define SP_THR 1024                                        // spmm block size

typedef _Float16 h4 __attribute__((ext_vector_type(4)));   // 8B vector of fp16

// NOTE (r3): __builtin_nontemporal_load on gfx950 = last-use/invalidating;
// on dirty lines -> ~35x WRITE amplification. Plain loads only.
// NOTE (r4): per-edge global atomics cost ~32B HBM each. Aggregate in LDS.
// NOTE (r6): gather is DRAM-efficiency bound; only byte reduction helps.
// NOTE (r7): fp16 gather sources halve bytes; absmax unchanged (1.5e-5).
// NOTE (r8 post-mortem): shrinking buckets degraded bucket_agg's segment
// writes to ~56B scatter (+45us total). r9 removes the row-sort (place)
// entirely: spmm accumulates per-bucket in a 128KB LDS fp32 tile reading
// UNSORTED segments, so no CSR/row_ptr is needed at all.

__device__ __forceinline__ int wave_incl_scan(int v, int lane) {
#pragma unroll
    for (int d = 1; d < 64; d <<= 1) {
        int t = __shfl_up(v, d, 64);
        if (lane >= d) v += t;
    }
    return v;
}

// ===========================================================================
// binning: 4096 edges/block -> coarse-bucket segments via LDS counting-sort;
// one global atomic per (block,bucket); coalesced run writes into segments.
// pay.x packs col(19b) | rlo(9b)<<19 ; pay.y = val.
// ===========================================================================
__global__ __launch_bounds__(AGG_THR)
void bucket_agg_kernel(const int*   __restrict__ rows,
                       const int*   __restrict__ cols,
                       const float* __restrict__ vals,
                       int*         __restrict__ bcnt,   // [NBUCK*16] zeroed
                       float2*      __restrict__ pay) {  // [NBUCK*SEGCAP]
    __shared__ int            cntS[NB2];
    __shared__ int            hoff[NB2];
    __shared__ int            waveTotS[8];
    __shared__ float2         payS[AGG_T];
    __shared__ unsigned short bidS[AGG_T];

    int tid  = threadIdx.x;
    int lane = tid & 63;
    int wid  = tid >> 6;
    int base = blockIdx.x * AGG_T;

    cntS[tid]       = 0;
    cntS[tid + 512] = 0;
    __syncthreads();

    // phase A: count
    unsigned pk[AGG_EPT];
#pragma unroll
    for (int j = 0; j < AGG_EPT; j++) {
        int e = base + j * AGG_THR + tid;
        pk[j] = 0xFFFFFFFFu;
        if (e < NNZ) {
            int r  = rows[e];
            int b  = r >> BSHIFT;                    // 10 bits
            int lp = atomicAdd(&cntS[b], 1);         // <= 4095, 12 bits
            pk[j]  = ((unsigned)b << 21) | ((unsigned)(r & (BROWS - 1)) << 12)
                   | (unsigned)lp;
        }
    }
    __syncthreads();

    // blocked exclusive scan of cntS[0..1023] (2 slots/thread) via shfl
    int v0 = cntS[2 * tid];
    int v1 = cntS[2 * tid + 1];
    int pv = v0 + v1;
    int incl = wave_incl_scan(pv, lane);
    if (lane == 63) waveTotS[wid] = incl;
    __syncthreads();
    int wbase = 0;
    for (int w = 0; w < wid; w++) wbase += waveTotS[w];
    int excl0 = wbase + incl - pv;
    int excl1 = excl0 + v0;

    if (2 * tid     < NBUCK && v0 > 0) hoff[2 * tid    ] = atomicAdd(&bcnt[(2 * tid    ) * 16], v0);
    if (2 * tid + 1 < NBUCK && v1 > 0) hoff[2 * tid + 1] = atomicAdd(&bcnt[(2 * tid + 1) * 16], v1);
    cntS[2 * tid]     = excl0;
    cntS[2 * tid + 1] = excl1;
    __syncthreads();

    // phase B: stage into LDS at counting-sort position
#pragma unroll
    for (int j = 0; j < AGG_EPT; j++) {
        if (pk[j] != 0xFFFFFFFFu) {
            int e   = base + j * AGG_THR + tid;
            int b   = pk[j] >> 21;
            int rl  = (pk[j] >> 12) & (BROWS - 1);
            int lp  = pk[j] & 0xFFF;
            int idx = cntS[b] + lp;
            unsigned packed = (unsigned)cols[e] | ((unsigned)rl << 19);
            payS[idx] = make_float2(__uint_as_float(packed), vals[e]);
            bidS[idx] = (unsigned short)b;
        }
    }
    __syncthreads();

    // write-out: contiguous per-bucket runs into fixed segments
    int total = NNZ - base; if (total > AGG_T) total = AGG_T;
    for (int i = tid; i < total; i += AGG_THR) {
        int b   = bidS[i];
        int pos = hoff[b] + (i - cntS[b]);
        if (pos < SEGCAP)   // 16-sigma safety clamp
            pay[(size_t)b * SEGCAP + pos] = payS[i];
    }
}

// fp16 embedding shadow: eh = fp16(concat(user, item))
__global__ void initH_kernel(const float* __restrict__ user_t,
                             const float* __restrict__ item_t,
                             _Float16* __restrict__ eh) {
    int i = blockIdx.x * blockDim.x + threadIdx.x;
    const int total4 = N_NODES * EMB / 4;
    if (i >= total4) return;
    int fi   = i * 4;
    int node = fi >> 6;
    int off  = fi & 63;
    float4 v;
    if (node < N_USERS)
        v = *(const float4*)(user_t + (size_t)node * EMB + off);
    else
        v = *(const float4*)(item_t + (size_t)(node - N_USERS) * EMB + off);
    h4 h = { (_Float16)v.x, (_Float16)v.y, (_Float16)v.z, (_Float16)v.w };
    *(h4*)(eh + fi) = h;
}

// ===========================================================================
// SpMM via LDS accumulator tile: persistent blocks (grid=256), ticket loop
// over buckets. Per bucket: zero 128KB fp32 tile; stream UNSORTED segment;
// per edge a 16-lane group gathers the 128B fp16 x-row and LDS-atomicAdds
// val*x into acc[rlo][*]; then the tile is streamed out coalesced.
// ===========================================================================
__device__ __forceinline__ void acc_segment(const float2*  __restrict__ seg,
                                            const _Float16* __restrict__ xh,
                                            float* accS, int run, int g, int l) {
    int e = g;
    for (; e + 64 < run; e += 128) {
        float2 ed0 = seg[e];
        float2 ed1 = seg[e + 64];
        unsigned u0 = __float_as_uint(ed0.x);
        unsigned u1 = __float_as_uint(ed1.x);
        h4 x0 = *(const h4*)(xh + ((size_t)(u0 & 0x7FFFF) << 6) + (l << 2));
        h4 x1 = *(const h4*)(xh + ((size_t)(u1 & 0x7FFFF) << 6) + (l << 2));
        float* a0 = accS + ((u0 >> 19) << 6) + (l << 2);
        float* a1 = accS + ((u1 >> 19) << 6) + (l << 2);
        atomicAdd(a0 + 0, ed0.y * (float)x0.x);
        atomicAdd(a0 + 1, ed0.y * (float)x0.y);
        atomicAdd(a0 + 2, ed0.y * (float)x0.z);
        atomicAdd(a0 + 3, ed0.y * (float)x0.w);
        atomicAdd(a1 + 0, ed1.y * (float)x1.x);
        atomicAdd(a1 + 1, ed1.y * (float)x1.y);
        atomicAdd(a1 + 2, ed1.y * (float)x1.z);
        atomicAdd(a1 + 3, ed1.y * (float)x1.w);
    }
    if (e < run) {
        float2 ed0 = seg[e];
        unsigned u0 = __float_as_uint(ed0.x);
        h4 x0 = *(const h4*)(xh + ((size_t)(u0 & 0x7FFFF) << 6) + (l << 2));
        float* a0 = accS + ((u0 >> 19) << 6) + (l << 2);
        atomicAdd(a0 + 0, ed0.y * (float)x0.x);
        atomicAdd(a0 + 1, ed0.y * (float)x0.y);
        atomicAdd(a0 + 2, ed0.y * (float)x0.z);
        atomicAdd(a0 + 3, ed0.y * (float)x0.w);
    }
}

// layers 1,2: y_h = fp16(A * x_h)
__global__ __launch_bounds__(SP_THR)
void spmm_acc_y_kernel(const int*      __restrict__ bcnt,
                       const float2*   __restrict__ pay,
                       const _Float16* __restrict__ xh,
                       _Float16*       __restrict__ yh,
                       int*            __restrict__ ticket) {
    __shared__ float accS[BROWS * EMB];   // 131072 B
    __shared__ int   bS;
    int tid = threadIdx.x;
    int g   = tid >> 4;
    int l   = tid & 15;
    int b   = blockIdx.x;
    while (b < NBUCK) {
        for (int i = tid; i < BROWS * EMB; i += SP_THR) accS[i] = 0.f;
        __syncthreads();
        int run = bcnt[b * 16]; if (run > SEGCAP) run = SEGCAP;
        acc_segment(pay + (size_t)b * SEGCAP, xh, accS, run, g, l);
        __syncthreads();
        int r0   = b << BSHIFT;
        int nrow = N_NODES - r0; if (nrow > BROWS) nrow = BROWS;
        int n4   = nrow << 4;                     // h4 chunks
        for (int i = tid; i < n4; i += SP_THR) {
            int li = i << 2;
            float4 a = *(float4*)&accS[li];
            h4 h = { (_Float16)a.x, (_Float16)a.y, (_Float16)a.z, (_Float16)a.w };
            *(h4*)(yh + ((size_t)r0 << 6) + li) = h;
        }
        if (tid == 0) bS = 256 + atomicAdd(ticket, 1);
        __syncthreads();
        b = bS;
    }
}

// layer 3 fused final: out = (e_fp32 + y1 + y2 + A*y2) / 4
__global__ __launch_bounds__(SP_THR)
void spmm_acc_fin_kernel(const int*      __restrict__ bcnt,
                         const float2*   __restrict__ pay,
                         const float*    __restrict__ user_t,
                         const float*    __restrict__ item_t,
                         const _Float16* __restrict__ y1h,
                         const _Float16* __restrict__ y2h,
                         float*          __restrict__ out,
                         int*            __restrict__ ticket) {
    __shared__ float accS[BROWS * EMB];   // 131072 B
    __shared__ int   bS;
    int tid = threadIdx.x;
    int g   = tid >> 4;
    int l   = tid & 15;
    int b   = blockIdx.x;
    while (b < NBUCK) {
        for (int i = tid; i < BROWS * EMB; i += SP_THR) accS[i] = 0.f;
        __syncthreads();
        int run = bcnt[b * 16]; if (run > SEGCAP) run = SEGCAP;
        acc_segment(pay + (size_t)b * SEGCAP, y2h, accS, run, g, l);
        __syncthreads();
        int r0   = b << BSHIFT;
        int nrow = N_NODES - r0; if (nrow > BROWS) nrow = BROWS;
        int n4   = nrow << 4;
        for (int i = tid; i < n4; i += SP_THR) {
            int li = i << 2;
            int gr = r0 + (li >> 6);
            size_t o = ((size_t)r0 << 6) + li;
            float4 a = *(float4*)&accS[li];
            float4 ev = (gr < N_USERS)
                      ? *(const float4*)(user_t + o)
                      : *(const float4*)(item_t + o - ((size_t)N_USERS << 6));
            h4 v1 = *(const h4*)(y1h + o);
            h4 v2 = *(const h4*)(y2h + o);
            float4 r;
            r.x = (ev.x + (float)v1.x + (float)v2.x + a.x) * 0.25f;
            r.y = (ev.y + (float)v1.y + (float)v2.y + a.y) * 0.25f;
            r.z = (ev.z + (float)v1.z + (float)v2.z + a.z) * 0.25f;
            r.w = (ev.w + (float)v1.w + (float)v2.w + a.w) * 0.25f;
            *(float4*)(out + o) = r;
        }
        if (tid == 0) bS = 256 + atomicAdd(ticket, 1);
        __syncthreads();
        b = bS;
    }
}

// ===========================================================================
// Fallback atomic path (tiny ws only)
// ===========================================================================
__global__ void init_kernel(const float* __restrict__ user_t,
                            const float* __restrict__ item_t,
                            float* __restrict__ out,
                            float* __restrict__ bufA,
                            float* __restrict__ bufB) {
    int i = blockIdx.x * blockDim.x + threadIdx.x;
    const int total4 = N_NODES * EMB / 4;
    if (i >= total4) return;
    int fi   = i * 4;
    int node = fi >> 6;
    int off  = fi & 63;
    float4 v;
    if (node < N_USERS)
        v = *(const float4*)(user_t + (size_t)node * EMB + off);
    else
        v = *(const float4*)(item_t + (size_t)(node - N_USERS) * EMB + off);
    *(float4*)(out  + fi) = v;
    *(float4*)(bufA + fi) = v;
    *(float4*)(bufB + fi) = make_float4(0.f, 0.f, 0.f, 0.f);
}

__global__ void spmm_kernel(const int*   __restrict__ rows,
                            const int*   __restrict__ cols,
                            const float* __restrict__ vals,
                            const float* __restrict__ x,
                            float*       __restrict__ y) {
    int tid  = blockIdx.x * blockDim.x + threadIdx.x;
    int e    = tid >> 6;
    int lane = tid & 63;
    if (e >= NNZ) return;
    atomicAdd(&y[(size_t)rows[e] * EMB + lane], vals[e] * x[(size_t)cols[e] * EMB + lane]);
}

__global__ void acc_zero_kernel(float* __restrict__ out,
                                const float* __restrict__ src,
                                float* __restrict__ zbuf) {
    int i = blockIdx.x * blockDim.x + threadIdx.x;
    const int total4 = N_NODES * EMB / 4;
    if (i >= total4) return;
    int fi = i * 4;
    float4 o = *(float4*)(out + fi);
    float4 s = *(const float4*)(src + fi);
    o.x += s.x; o.y += s.y; o.z += s.z; o.w += s.w;
    *(float4*)(out  + fi) = o;
    *(float4*)(zbuf + fi) = make_float4(0.f, 0.f, 0.f, 0.f);
}

__global__ void final_kernel(float* __restrict__ out,
                             const float* __restrict__ src) {
    int i = blockIdx.x * blockDim.x + threadIdx.x;
    const int total4 = N_NODES * EMB / 4;
    if (i >= total4) return;
    int fi = i * 4;
    float4 o = *(float4*)(out + fi);
    float4 s = *(const float4*)(src + fi);
    o.x = (o.x + s.x) * 0.25f;
    o.y = (o.y + s.y) * 0.25f;
    o.z = (o.z + s.z) * 0.25f;
    o.w = (o.w + s.w) * 0.25f;
    *(float4*)(out + fi) = o;
}

// ===========================================================================
extern "C" void kernel_launch(void* const* d_in, const int* in_sizes, int n_in,
                              void* d_out, int out_size, void* d_ws, size_t ws_size,
                              hipStream_t stream) {
    const float* user_t = (const float*)d_in[0];
    const float* item_t = (const float*)d_in[1];
    const int*   rows   = (const int*)d_in[2];
    const int*   cols   = (const int*)d_in[3];
    const float* vals   = (const float*)d_in[4];
    float* out = (float*)d_out;

    const size_t embh_bytes  = (size_t)N_NODES * EMB * 2;         // 38.4 MB
    const size_t emb_bytes   = (size_t)N_NODES * EMB * 4;         // 76.8 MB
    const size_t pay_bytes   = (size_t)NBUCK * SEGCAP * 8;        // 38.4 MB
    const size_t ctl_bytes   = ((size_t)NBUCK * 16 + 48) * 4;     // bcnt + tickets
    const int total4    = N_NODES * EMB / 4;
    const int ew_blocks = (total4 + 255) / 256;

    const size_t need_h = pay_bytes + 3 * embh_bytes + ctl_bytes; // ~154 MB

    if (ws_size >= need_h) {
        // ---- LDS-accumulator tier ----
        char* p = (char*)d_ws;
        float2*   pay = (float2*)p;   p += pay_bytes;
        _Float16* eh  = (_Float16*)p; p += embh_bytes;
        _Float16* y1h = (_Float16*)p; p += embh_bytes;
        _Float16* y2h = (_Float16*)p; p += embh_bytes;
        int*      bcnt = (int*)p;
        int*      tk0  = bcnt + (size_t)NBUCK * 16;
        int*      tk1  = tk0 + 16;
        int*      tk2  = tk0 + 32;

        hipMemsetAsync(bcnt, 0, ctl_bytes, stream);
        bucket_agg_kernel<<<AGG_BLOCKS, AGG_THR, 0, stream>>>(rows, cols, vals, bcnt, pay);
        initH_kernel<<<ew_blocks, 256, 0, stream>>>(user_t, item_t, eh);

        spmm_acc_y_kernel  <<<256, SP_THR, 0, stream>>>(bcnt, pay, eh,  y1h, tk0);
        spmm_acc_y_kernel  <<<256, SP_THR, 0, stream>>>(bcnt, pay, y1h, y2h, tk1);
        spmm_acc_fin_kernel<<<256, SP_THR, 0, stream>>>(bcnt, pay, user_t, item_t,
                                                        y1h, y2h, out, tk2);
    } else {
        // ---- tiny-ws fallback ----
        char* p = (char*)d_ws;
        float* bufA = (float*)p; p += emb_bytes;
        float* bufB = (float*)p;
        const int spmmA_blocks = (int)(((size_t)NNZ * 64 + 255) / 256);
        init_kernel<<<ew_blocks, 256, 0, stream>>>(user_t, item_t, out, bufA, bufB);
        spmm_kernel<<<spmmA_blocks, 256, 0, stream>>>(rows, cols, vals, bufA, bufB);
        acc_zero_kernel<<<ew_blocks, 256, 0, stream>>>(out, bufB, bufA);
        spmm_kernel<<<spmmA_blocks, 256, 0, stream>>>(rows, cols, vals, bufB, bufA);
        acc_zero_kernel<<<ew_blocks, 256, 0, stream>>>(out, bufA, bufB);
        spmm_kernel<<<spmmA_blocks, 256, 0, stream>>>(rows, cols, vals, bufA, bufB);
        final_kernel<<<ew_blocks, 256, 0, stream>>>(out, bufB);
    }
}

// Round 10
// 538.080 us; speedup vs baseline: 9.6642x; 9.6642x over previous
//
#include <hip/hip_runtime.h>

#define N_USERS 100000
#define N_ITEMS 200000
#define N_NODES (N_USERS + N_ITEMS)
#define EMB     64
#define NNZ     4000000

// coarse row-buckets: 1024 rows each (r8 showed 512-row buckets degrade
// bucket_agg's segment writes to sub-line scatter: keep 1024)
#define BSHIFT 10
#define BROWS  (1 << BSHIFT)                               // 1024 rows / bucket
#define NBUCK  ((N_NODES + BROWS - 1) >> BSHIFT)           // 293

// block-aggregated binning pass
#define AGG_THR    512
#define AGG_EPT    8
#define AGG_T      (AGG_THR * AGG_EPT)                     // 4096 edges / block
#define AGG_BLOCKS ((NNZ + AGG_T - 1) / AGG_T)             // 977
#define SCAN_N     512                                     // pow2 >= NBUCK

// bucket segment capacity (mean fill 13652, sigma ~117 -> +23 sigma headroom)
#define SEGCAP 16384
#define PCAP   SEGCAP
#define PITER  (PCAP / 1024)                               // 16

typedef _Float16 h4 __attribute__((ext_vector_type(4)));   // 8B vector of fp16

// NOTE (r3): __builtin_nontemporal_load on gfx950 = last-use/invalidating;
// on dirty lines -> ~35x WRITE amplification. Plain loads only.
// NOTE (r4): per-edge global atomics cost ~32B HBM each. Aggregate in LDS.
// NOTE (r6): gather is DRAM-efficiency bound; only byte reduction helps.
// NOTE (r7): fp16 gather sources halve bytes; absmax unchanged (1.5e-5).
// NOTE (r8): 512-row buckets -> bucket_agg writes ~56B runs -> +45us. Keep 1024.
// NOTE (r9): LDS fp32 atomicAdd SpMM = 15x SLOWER (1678us/pass, VALUBusy 2%,
// 1 blk/CU). Row-sorted CSR + register accumulation is the right structure.

__device__ __forceinline__ int wave_incl_scan(int v, int lane) {
#pragma unroll
    for (int d = 1; d < 64; d <<= 1) {
        int t = __shfl_up(v, d, 64);
        if (lane >= d) v += t;
    }
    return v;
}

// ===========================================================================
// CSR build (histogram-free, bucket-segmented)
// ===========================================================================
// pass 1: bin 4096 edges/block into coarse buckets via LDS counting-sort;
// one global atomic per (block,bucket); coalesced run writes into segments.
// pk = b(9b)<<22 | rlo(10b)<<12 | lp(12b). pay.x packs col(19b) | rlo<<19.
__global__ __launch_bounds__(AGG_THR)
void bucket_agg_kernel(const int*   __restrict__ rows,
                       const int*   __restrict__ cols,
                       const float* __restrict__ vals,
                       int*         __restrict__ bcnt,   // [NBUCK*16] zeroed
                       float2*      __restrict__ pay) {  // [NBUCK*SEGCAP]
    __shared__ int            cntS[SCAN_N];
    __shared__ int            hoff[SCAN_N];
    __shared__ int            waveTotS[8];
    __shared__ float2         payS[AGG_T];    // 32KB
    __shared__ unsigned short bidS[AGG_T];    // 8KB

    int tid  = threadIdx.x;
    int lane = tid & 63;
    int wid  = tid >> 6;
    int base = blockIdx.x * AGG_T;

    cntS[tid] = 0;
    __syncthreads();

    // phase A: count (keep per-edge bucket/row-lo/local-pos packed in regs)
    unsigned pk[AGG_EPT];
#pragma unroll
    for (int j = 0; j < AGG_EPT; j++) {
        int e = base + j * AGG_THR + tid;
        pk[j] = 0xFFFFFFFFu;
        if (e < NNZ) {
            int r  = rows[e];
            int b  = r >> BSHIFT;                    // 9 bits
            int lp = atomicAdd(&cntS[b], 1);         // <= 4095, 12 bits
            pk[j]  = ((unsigned)b << 22) | ((unsigned)(r & (BROWS - 1)) << 12)
                   | (unsigned)lp;
        }
    }
    __syncthreads();

    // exclusive scan of cntS[0..511] via shfl (2 barriers instead of 18)
    int v    = cntS[tid];
    int incl = wave_incl_scan(v, lane);
    if (lane == 63) waveTotS[wid] = incl;
    __syncthreads();
    int wbase = 0;
    for (int w = 0; w < wid; w++) wbase += waveTotS[w];
    int excl = wbase + incl - v;

    // reserve segment runs (one atomic per non-empty bucket)
    if (tid < NBUCK && v > 0) hoff[tid] = atomicAdd(&bcnt[tid * 16], v);
    cntS[tid] = excl;
    __syncthreads();

    // phase B: stage into LDS at counting-sort position
#pragma unroll
    for (int j = 0; j < AGG_EPT; j++) {
        if (pk[j] != 0xFFFFFFFFu) {
            int e   = base + j * AGG_THR + tid;
            int b   = pk[j] >> 22;
            int rl  = (pk[j] >> 12) & (BROWS - 1);
            int lp  = pk[j] & 0xFFF;
            int idx = cntS[b] + lp;
            unsigned packed = (unsigned)cols[e] | ((unsigned)rl << 19);
            payS[idx] = make_float2(__uint_as_float(packed), vals[e]);
            bidS[idx] = (unsigned short)b;
        }
    }
    __syncthreads();

    // write-out: contiguous per-bucket runs into fixed segments
    int total = NNZ - base; if (total > AGG_T) total = AGG_T;
    for (int i = tid; i < total; i += AGG_THR) {
        int b   = bidS[i];
        int pos = hoff[b] + (i - cntS[b]);
        if (pos < SEGCAP)   // 23-sigma safety clamp
            pay[(size_t)b * SEGCAP + pos] = payS[i];
    }
}

// tiny pass: exclusive-scan the 293 bucket totals -> bbase; seal row_ptr end.
__global__ void bscan_kernel(const int* __restrict__ bcnt,
                             int* __restrict__ bbase,
                             int* __restrict__ row_ptr) {
    __shared__ int s[512];
    int tid = threadIdx.x;
    int v = 0;
    if (tid < NBUCK) {
        v = bcnt[tid * 16];
        if (v > SEGCAP) v = SEGCAP;
    }
    s[tid] = v;
    __syncthreads();
    for (int off = 1; off < 512; off <<= 1) {
        int t = 0;
        if (tid >= off) t = s[tid - off];
        __syncthreads();
        if (tid >= off) s[tid] += t;
        __syncthreads();
    }
    if (tid < NBUCK) bbase[tid] = s[tid] - v;
    if (tid == 511) bbase[NBUCK] = s[511];
    if (tid == 0)   row_ptr[N_NODES] = NNZ;
}

// pass 2: one block per coarse bucket. Counting-sort the bucket's segment by
// row ENTIRELY IN LDS, emit row_ptr slice, stream sorted run out coalesced.
// Phase D also builds the fp16 shadow eh for this bucket's rows (replaces
// the separate initH pass). ALIASING NOTE: eh's per-bucket range coincides
// exactly with pay segment b (both 128KB/bucket); block b fully consumes its
// segment into registers (phase A) before phase D overwrites it.
__global__ __launch_bounds__(1024)
void place_kernel(const int*    __restrict__ bcnt,
                  const int*    __restrict__ bbase,
                  const float2* __restrict__ pay,
                  int*          __restrict__ row_ptr,
                  float2*       __restrict__ edges,
                  const float*  __restrict__ user_t,
                  const float*  __restrict__ item_t,
                  _Float16*     __restrict__ eh) {
    __shared__ float2 payS[PCAP];   // 131072 B
    __shared__ int    cntS[BROWS];  //   4096 B
    __shared__ int    waveTotS[16];
    int b    = blockIdx.x;
    int tid  = threadIdx.x;
    int lane = tid & 63;
    int wid  = tid >> 6;
    int run  = bcnt[b * 16]; if (run > PCAP) run = PCAP;
    int beg  = bbase[b];
    const float2* seg = pay + (size_t)b * SEGCAP;

    cntS[tid] = 0;
    __syncthreads();

    // phase A: pull edges into registers (fully unrolled -> static indexing),
    // histogram rows; atomic return value = within-row slot.
    unsigned eu[PITER]; float ev[PITER]; int elp[PITER];
#pragma unroll
    for (int j = 0; j < PITER; j++) {
        int i = j * 1024 + tid;
        eu[j] = 0xFFFFFFFFu;
        if (i < run) {
            float2 p = seg[i];
            unsigned u = __float_as_uint(p.x);
            eu[j] = u;
            ev[j] = p.y;
            elp[j] = atomicAdd(&cntS[(u >> 19) & (BROWS - 1)], 1);
        }
    }
    __syncthreads();

    // inclusive scan of 1024 row-counts via shfl (2 barriers instead of 20)
    int v    = cntS[tid];
    int incl = wave_incl_scan(v, lane);
    if (lane == 63) waveTotS[wid] = incl;
    __syncthreads();
    int wbase = 0;
    for (int w = 0; w < wid; w++) wbase += waveTotS[w];
    incl += wbase;
    cntS[tid] = incl;   // inclusive; exclusive(r) = cntS[r-1]

    // emit row_ptr slice (coalesced)
    int gr = (b << BSHIFT) + tid;
    if (gr < N_NODES) row_ptr[gr] = beg + incl - v;
    __syncthreads();

    // phase B: scatter into LDS at final sorted position
#pragma unroll
    for (int j = 0; j < PITER; j++) {
        if (eu[j] != 0xFFFFFFFFu) {
            int r    = (int)((eu[j] >> 19) & (BROWS - 1));
            int base = (r == 0) ? 0 : cntS[r - 1];
            payS[base + elp[j]] = make_float2(__uint_as_float(eu[j] & 0x7FFFFu), ev[j]);
        }
    }
    __syncthreads();

    // phase C: stream out sequentially — full-line coalesced stores
    for (int i = tid; i < run; i += 1024) {
        edges[beg + i] = payS[i];
    }

    // phase D: build fp16 shadow for this bucket's rows (coalesced stream)
    int r0   = b << BSHIFT;
    int nrow = N_NODES - r0; if (nrow > BROWS) nrow = BROWS;
    if (nrow > 0) {
        int nel = nrow << 6;
        for (int i = tid; i < nel; i += 1024) {
            int gr2 = r0 + (i >> 6);
            int d   = i & 63;
            float x = (gr2 < N_USERS)
                    ? user_t[(size_t)gr2 * EMB + d]
                    : item_t[(size_t)(gr2 - N_USERS) * EMB + d];
            eh[(size_t)r0 * EMB + i] = (_Float16)x;
        }
    }
}

// ===========================================================================
// SpMM core: fp16 gather source (128B/row), fp32 accumulate.
// ===========================================================================
__device__ __forceinline__ float4 row_gather_h(const int*      __restrict__ rp,
                                               const float2*   __restrict__ edges,
                                               const _Float16* __restrict__ xh,
                                               int row, int s) {
    int i   = rp[row];
    int end = rp[row + 1];
    float4 acc = make_float4(0.f, 0.f, 0.f, 0.f);
    for (; i + 3 < end; i += 4) {
        float2 e0 = edges[i];
        float2 e1 = edges[i + 1];
        float2 e2 = edges[i + 2];
        float2 e3 = edges[i + 3];
        h4 a = *(const h4*)(xh + ((size_t)__float_as_int(e0.x) << 6) + (s << 2));
        h4 b = *(const h4*)(xh + ((size_t)__float_as_int(e1.x) << 6) + (s << 2));
        h4 c = *(const h4*)(xh + ((size_t)__float_as_int(e2.x) << 6) + (s << 2));
        h4 d = *(const h4*)(xh + ((size_t)__float_as_int(e3.x) << 6) + (s << 2));
        acc.x += e0.y * (float)a.x + e1.y * (float)b.x + e2.y * (float)c.x + e3.y * (float)d.x;
        acc.y += e0.y * (float)a.y + e1.y * (float)b.y + e2.y * (float)c.y + e3.y * (float)d.y;
        acc.z += e0.y * (float)a.z + e1.y * (float)b.z + e2.y * (float)c.z + e3.y * (float)d.z;
        acc.w += e0.y * (float)a.w + e1.y * (float)b.w + e2.y * (float)c.w + e3.y * (float)d.w;
    }
    for (; i < end; ++i) {
        float2 e0 = edges[i];
        h4 a = *(const h4*)(xh + ((size_t)__float_as_int(e0.x) << 6) + (s << 2));
        acc.x += e0.y * (float)a.x;
        acc.y += e0.y * (float)a.y;
        acc.z += e0.y * (float)a.z;
        acc.w += e0.y * (float)a.w;
    }
    return acc;
}

// layers 1,2: y_h = fp16(A * x_h)
__global__ void spmm_yh_kernel(const int*      __restrict__ rp,
                               const float2*   __restrict__ edges,
                               const _Float16* __restrict__ xh,
                               _Float16*       __restrict__ yh) {
    int t    = blockIdx.x * blockDim.x + threadIdx.x;
    int wid  = t >> 6;
    int lane = t & 63;
    int q    = lane >> 4;
    int s    = lane & 15;
    int row  = (wid << 2) + q;
    if (row >= N_NODES) return;
    float4 acc = row_gather_h(rp, edges, xh, row, s);
    h4 h = { (_Float16)acc.x, (_Float16)acc.y, (_Float16)acc.z, (_Float16)acc.w };
    *(h4*)(yh + (((size_t)row << 6) + (s << 2))) = h;
}

// layer 3 fused final: out = (e_fp32 + y1 + y2 + A*y2) / 4
__global__ void spmm_fin_kernel(const int*      __restrict__ rp,
                                const float2*   __restrict__ edges,
                                const float*    __restrict__ user_t,
                                const float*    __restrict__ item_t,
                                const _Float16* __restrict__ y1h,
                                const _Float16* __restrict__ y2h,
                                float*          __restrict__ out) {
    int t    = blockIdx.x * blockDim.x + threadIdx.x;
    int wid  = t >> 6;
    int lane = t & 63;
    int q    = lane >> 4;
    int s    = lane & 15;
    int row  = (wid << 2) + q;
    if (row >= N_NODES) return;
    float4 acc = row_gather_h(rp, edges, y2h, row, s);
    size_t o = ((size_t)row << 6) + (s << 2);
    float4 ev;
    if (row < N_USERS)
        ev = *(const float4*)(user_t + o);
    else
        ev = *(const float4*)(item_t + o - ((size_t)N_USERS << 6));
    h4 v1 = *(const h4*)(y1h + o);
    h4 v2 = *(const h4*)(y2h + o);
    float4 r;
    r.x = (ev.x + (float)v1.x + (float)v2.x + acc.x) * 0.25f;
    r.y = (ev.y + (float)v1.y + (float)v2.y + acc.y) * 0.25f;
    r.z = (ev.z + (float)v1.z + (float)v2.z + acc.z) * 0.25f;
    r.w = (ev.w + (float)v1.w + (float)v2.w + acc.w) * 0.25f;
    *(float4*)(out + o) = r;
}

// ===========================================================================
// Fallback atomic path (tiny ws only)
// ===========================================================================
__global__ void init_kernel(const float* __restrict__ user_t,
                            const float* __restrict__ item_t,
                            float* __restrict__ out,
                            float* __restrict__ bufA,
                            float* __restrict__ bufB) {
    int i = blockIdx.x * blockDim.x + threadIdx.x;
    const int total4 = N_NODES * EMB / 4;
    if (i >= total4) return;
    int fi   = i * 4;
    int node = fi >> 6;
    int off  = fi & 63;
    float4 v;
    if (node < N_USERS)
        v = *(const float4*)(user_t + (size_t)node * EMB + off);
    else
        v = *(const float4*)(item_t + (size_t)(node - N_USERS) * EMB + off);
    *(float4*)(out  + fi) = v;
    *(float4*)(bufA + fi) = v;
    *(float4*)(bufB + fi) = make_float4(0.f, 0.f, 0.f, 0.f);
}

__global__ void spmm_kernel(const int*   __restrict__ rows,
                            const int*   __restrict__ cols,
                            const float* __restrict__ vals,
                            const float* __restrict__ x,
                            float*       __restrict__ y) {
    int tid  = blockIdx.x * blockDim.x + threadIdx.x;
    int e    = tid >> 6;
    int lane = tid & 63;
    if (e >= NNZ) return;
    atomicAdd(&y[(size_t)rows[e] * EMB + lane], vals[e] * x[(size_t)cols[e] * EMB + lane]);
}

__global__ void acc_zero_kernel(float* __restrict__ out,
                                const float* __restrict__ src,
                                float* __restrict__ zbuf) {
    int i = blockIdx.x * blockDim.x + threadIdx.x;
    const int total4 = N_NODES * EMB / 4;
    if (i >= total4) return;
    int fi = i * 4;
    float4 o = *(float4*)(out + fi);
    float4 s = *(const float4*)(src + fi);
    o.x += s.x; o.y += s.y; o.z += s.z; o.w += s.w;
    *(float4*)(out  + fi) = o;
    *(float4*)(zbuf + fi) = make_float4(0.f, 0.f, 0.f, 0.f);
}

__global__ void final_kernel(float* __restrict__ out,
                             const float* __restrict__ src) {
    int i = blockIdx.x * blockDim.x + threadIdx.x;
    const int total4 = N_NODES * EMB / 4;
    if (i >= total4) return;
    int fi = i * 4;
    float4 o = *(float4*)(out + fi);
    float4 s = *(const float4*)(src + fi);
    o.x = (o.x + s.x) * 0.25f;
    o.y = (o.y + s.y) * 0.25f;
    o.z = (o.z + s.z) * 0.25f;
    o.w = (o.w + s.w) * 0.25f;
    *(float4*)(out + fi) = o;
}

// ===========================================================================
extern "C" void kernel_launch(void* const* d_in, const int* in_sizes, int n_in,
                              void* d_out, int out_size, void* d_ws, size_t ws_size,
                              hipStream_t stream) {
    const float* user_t = (const float*)d_in[0];
    const float* item_t = (const float*)d_in[1];
    const int*   rows   = (const int*)d_in[2];
    const int*   cols   = (const int*)d_in[3];
    const float* vals   = (const float*)d_in[4];
    float* out = (float*)d_out;

    const size_t embh_bytes = (size_t)N_NODES * EMB * 2;          // 38.4 MB
    const size_t emb_bytes  = (size_t)N_NODES * EMB * 4;          // 76.8 MB
    const size_t pay_bytes  = (size_t)NBUCK * SEGCAP * 8;         // 38.4 MB
    const size_t r0_bytes   = (pay_bytes > embh_bytes ? pay_bytes : embh_bytes);
    const size_t edges_bytes = (size_t)NNZ * 8;                   // 32 MB
    const size_t small_bytes = (size_t)(N_NODES + 1) * 4
                             + (size_t)NBUCK * 16 * 4
                             + (size_t)(NBUCK + 1) * 4;
    const int total4    = N_NODES * EMB / 4;
    const int ew_blocks = (total4 + 255) / 256;

    const size_t need_h = r0_bytes + 2 * embh_bytes + edges_bytes + small_bytes; // ~148 MB
    const int spmm_blocks = (int)(((size_t)N_NODES / 4 * 64 + 255) / 256); // 18750

    if (ws_size >= need_h) {
        // ---- fp16-gather tier ----
        char* p = (char*)d_ws;
        char*     region0 = p;            p += r0_bytes;  // pay -> eh (aliased)
        _Float16* y1h     = (_Float16*)p; p += embh_bytes;
        _Float16* y2h     = (_Float16*)p; p += embh_bytes;
        float2*   edges   = (float2*)p;   p += edges_bytes;
        int*      row_ptr = (int*)p;      p += (size_t)(N_NODES + 1) * 4;
        int*      bcnt    = (int*)p;      p += (size_t)NBUCK * 16 * 4;
        int*      bbase   = (int*)p;
        float2*   pay = (float2*)region0;          // dead after place phase A
        _Float16* eh  = (_Float16*)region0;        // built by place phase D

        hipMemsetAsync(bcnt, 0, (size_t)NBUCK * 16 * 4, stream);
        bucket_agg_kernel<<<AGG_BLOCKS, AGG_THR, 0, stream>>>(rows, cols, vals, bcnt, pay);
        bscan_kernel<<<1, 512, 0, stream>>>(bcnt, bbase, row_ptr);
        place_kernel<<<NBUCK, 1024, 0, stream>>>(bcnt, bbase, pay, row_ptr, edges,
                                                 user_t, item_t, eh);

        spmm_yh_kernel <<<spmm_blocks, 256, 0, stream>>>(row_ptr, edges, eh,  y1h);
        spmm_yh_kernel <<<spmm_blocks, 256, 0, stream>>>(row_ptr, edges, y1h, y2h);
        spmm_fin_kernel<<<spmm_blocks, 256, 0, stream>>>(row_ptr, edges, user_t, item_t,
                                                         y1h, y2h, out);
    } else {
        // ---- tiny-ws fallback ----
        char* p = (char*)d_ws;
        float* bufA = (float*)p; p += emb_bytes;
        float* bufB = (float*)p;
        const int spmmA_blocks = (int)(((size_t)NNZ * 64 + 255) / 256);
        init_kernel<<<ew_blocks, 256, 0, stream>>>(user_t, item_t, out, bufA, bufB);
        spmm_kernel<<<spmmA_blocks, 256, 0, stream>>>(rows, cols, vals, bufA, bufB);
        acc_zero_kernel<<<ew_blocks, 256, 0, stream>>>(out, bufB, bufA);
        spmm_kernel<<<spmmA_blocks, 256, 0, stream>>>(rows, cols, vals, bufB, bufA);
        acc_zero_kernel<<<ew_blocks, 256, 0, stream>>>(out, bufA, bufB);
        spmm_kernel<<<spmmA_blocks, 256, 0, stream>>>(rows, cols, vals, bufA, bufB);
        final_kernel<<<ew_blocks, 256, 0, stream>>>(out, bufB);
    }
}

// Round 11
// 503.287 us; speedup vs baseline: 10.3323x; 1.0691x over previous
//
#include <hip/hip_runtime.h>

#define N_USERS 100000
#define N_ITEMS 200000
#define N_NODES (N_USERS + N_ITEMS)
#define EMB     64
#define NNZ     4000000

// coarse row-buckets: 1200 rows each -> NBUCK = 250 = one bucket per CU
// (r10/r11: 293 buckets at 1 blk/CU meant ceil(293/256)=2 occupancy rounds,
// ~43% idle tail in place. 250x1200 = 300000 exactly, no partial bucket.)
#define BROWS  1200
#define NBUCK  250
#define SCAN_N 512                                         // pow2 >= NBUCK

// block-aggregated binning pass
#define AGG_THR    512
#define AGG_EPT    8
#define AGG_T      (AGG_THR * AGG_EPT)                     // 4096 edges / block
#define AGG_BLOCKS ((NNZ + AGG_T - 1) / AGG_T)             // 977

// bucket segment capacity (mean fill 16000, sigma ~126 -> +11 sigma headroom)
#define SEGCAP 17408
#define PITER  17                                          // ceil(SEGCAP/1024)

typedef _Float16 h4 __attribute__((ext_vector_type(4)));   // 8B vector of fp16

// NOTE (r3): __builtin_nontemporal_load on gfx950 = last-use/invalidating;
// on dirty lines -> ~35x WRITE amplification. Plain loads only.
// NOTE (r4): per-edge global atomics cost ~32B HBM each. Aggregate in LDS.
// NOTE (r6): gather is DRAM-efficiency bound; only byte reduction helps.
// NOTE (r7): fp16 gather sources halve bytes; absmax unchanged (1.5e-5).
// NOTE (r8): smaller buckets degrade bucket_agg segment writes (sub-line).
// NOTE (r9): LDS fp32 atomicAdd SpMM = 15x SLOWER. Keep CSR + reg accum.
// NOTE (r10): fusing initH into place + shfl scans regressed (+26us);
// r7 build structure restored verbatim below, only bucket geometry changed.

// ===========================================================================
// CSR build (histogram-free, bucket-segmented)
// ===========================================================================
// pass 1: bin 4096 edges/block into coarse buckets via LDS counting-sort;
// one global atomic per (block,bucket); coalesced run writes into segments.
// pk = b(8b)<<23 | rlo(11b)<<12 | lp(12b). pay.x packs col(19b) | rlo<<19.
__global__ __launch_bounds__(AGG_THR)
void bucket_agg_kernel(const int*   __restrict__ rows,
                       const int*   __restrict__ cols,
                       const float* __restrict__ vals,
                       int*         __restrict__ bcnt,   // [NBUCK*16] zeroed
                       float2*      __restrict__ pay) {  // [NBUCK*SEGCAP]
    __shared__ int            cntS[SCAN_N];   // counts -> exclusive scan
    __shared__ int            hoff[SCAN_N];   // segment offset per bucket
    __shared__ float2         payS[AGG_T];    // staged (packed col, val)
    __shared__ unsigned short bidS[AGG_T];    // bucket id per staged slot

    int tid  = threadIdx.x;
    int base = blockIdx.x * AGG_T;

    cntS[tid] = 0;
    __syncthreads();

    // phase A: count (keep per-edge bucket/row-lo/local-pos packed in regs)
    unsigned pk[AGG_EPT];
#pragma unroll
    for (int j = 0; j < AGG_EPT; j++) {
        int e = base + j * AGG_THR + tid;
        pk[j] = 0xFFFFFFFFu;
        if (e < NNZ) {
            int r  = rows[e];
            int b  = r / BROWS;                      // 8 bits (const div)
            int rl = r - b * BROWS;                  // 11 bits
            int lp = atomicAdd(&cntS[b], 1);         // <= 4095, 12 bits
            pk[j]  = ((unsigned)b << 23) | ((unsigned)rl << 12) | (unsigned)lp;
        }
    }
    __syncthreads();

    // exclusive scan of cntS (SCAN_N == AGG_THR, one element per thread)
    int v = cntS[tid];
    for (int off = 1; off < SCAN_N; off <<= 1) {
        int t = 0;
        if (tid >= off) t = cntS[tid - off];
        __syncthreads();
        if (tid >= off) cntS[tid] += t;
        __syncthreads();
    }
    int excl = cntS[tid] - v;

    // reserve segment runs (one atomic per non-empty bucket)
    if (tid < NBUCK && v > 0) hoff[tid] = atomicAdd(&bcnt[tid * 16], v);
    __syncthreads();
    cntS[tid] = excl;
    __syncthreads();

    // phase B: stage into LDS at counting-sort position
#pragma unroll
    for (int j = 0; j < AGG_EPT; j++) {
        if (pk[j] != 0xFFFFFFFFu) {
            int e   = base + j * AGG_THR + tid;
            int b   = pk[j] >> 23;
            int rl  = (pk[j] >> 12) & 0x7FF;
            int lp  = pk[j] & 0xFFF;
            int idx = cntS[b] + lp;
            unsigned packed = (unsigned)cols[e] | ((unsigned)rl << 19);
            payS[idx] = make_float2(__uint_as_float(packed), vals[e]);
            bidS[idx] = (unsigned short)b;
        }
    }
    __syncthreads();

    // write-out: contiguous per-bucket runs into fixed segments
    int total = NNZ - base; if (total > AGG_T) total = AGG_T;
    for (int i = tid; i < total; i += AGG_THR) {
        int b   = bidS[i];
        int pos = hoff[b] + (i - cntS[b]);
        if (pos < SEGCAP)   // 11-sigma safety clamp
            pay[(size_t)b * SEGCAP + pos] = payS[i];
    }
}

// tiny pass: exclusive-scan the 250 bucket totals -> bbase; seal row_ptr end.
__global__ void bscan_kernel(const int* __restrict__ bcnt,
                             int* __restrict__ bbase,
                             int* __restrict__ row_ptr) {
    __shared__ int s[512];
    int tid = threadIdx.x;
    int v = 0;
    if (tid < NBUCK) {
        v = bcnt[tid * 16];
        if (v > SEGCAP) v = SEGCAP;
    }
    s[tid] = v;
    __syncthreads();
    for (int off = 1; off < 512; off <<= 1) {
        int t = 0;
        if (tid >= off) t = s[tid - off];
        __syncthreads();
        if (tid >= off) s[tid] += t;
        __syncthreads();
    }
    if (tid < NBUCK) bbase[tid] = s[tid] - v;
    if (tid == 511) bbase[NBUCK] = s[511];
    if (tid == 0)   row_ptr[N_NODES] = NNZ;
}

// pass 2: one block per 1200-row bucket (250 blocks = 1 occupancy round).
// Counting-sort the bucket's segment by row ENTIRELY IN LDS (~148KB), emit
// row_ptr slice, stream sorted run out -> full-line coalesced stores.
__global__ __launch_bounds__(1024)
void place_kernel(const int*    __restrict__ bcnt,
                  const int*    __restrict__ bbase,
                  const float2* __restrict__ pay,
                  int*          __restrict__ row_ptr,
                  float2*       __restrict__ edges) {
    __shared__ float2 payS[SEGCAP];   // 139264 B
    __shared__ int    cntS[2048];     //   8192 B (1200 used, rest zero)
    __shared__ int    sS[1024];       //   4096 B
    int b   = blockIdx.x;
    int tid = threadIdx.x;
    int run = bcnt[b * 16]; if (run > SEGCAP) run = SEGCAP;
    int beg = bbase[b];
    const float2* seg = pay + (size_t)b * SEGCAP;

    cntS[tid]        = 0;
    cntS[tid + 1024] = 0;
    __syncthreads();

    // phase A: pull edges into registers (fully unrolled -> static indexing),
    // histogram rows; atomic return value = within-row slot.
    unsigned eu[PITER]; float ev[PITER]; int elp[PITER];
#pragma unroll
    for (int j = 0; j < PITER; j++) {
        int i = j * 1024 + tid;
        eu[j] = 0xFFFFFFFFu;
        if (i < run) {
            float2 p = seg[i];
            unsigned u = __float_as_uint(p.x);
            eu[j] = u;
            ev[j] = p.y;
            elp[j] = atomicAdd(&cntS[u >> 19], 1);
        }
    }
    __syncthreads();

    // scan of 1200 row-counts: 2 slots/thread, Hillis-Steele over pair-sums
    int v0 = cntS[2 * tid];
    int v1 = cntS[2 * tid + 1];
    int pv = v0 + v1;
    sS[tid] = pv;
    __syncthreads();
    for (int off = 1; off < 1024; off <<= 1) {
        int t = 0;
        if (tid >= off) t = sS[tid - off];
        __syncthreads();
        if (tid >= off) sS[tid] += t;
        __syncthreads();
    }
    int excl = sS[tid] - pv;
    cntS[2 * tid]     = excl + v0;         // inclusive at slot 2t
    cntS[2 * tid + 1] = excl + v0 + v1;    // inclusive at slot 2t+1
    __syncthreads();

    // emit row_ptr slice (coalesced; 1200 rows, 2 iterations)
    int r0 = b * BROWS;
#pragma unroll
    for (int j = 0; j < 2; j++) {
        int lr = j * 1024 + tid;
        if (lr < BROWS)
            row_ptr[r0 + lr] = beg + (lr ? cntS[lr - 1] : 0);
    }

    // phase B: scatter into LDS at final sorted position
#pragma unroll
    for (int j = 0; j < PITER; j++) {
        if (eu[j] != 0xFFFFFFFFu) {
            int r    = (int)(eu[j] >> 19);
            int base = (r == 0) ? 0 : cntS[r - 1];
            payS[base + elp[j]] = make_float2(__uint_as_float(eu[j] & 0x7FFFFu), ev[j]);
        }
    }
    __syncthreads();

    // phase C: stream out sequentially — full-line coalesced stores
    for (int i = tid; i < run; i += 1024) {
        edges[beg + i] = payS[i];
    }
}

// ===========================================================================
// fp16 embedding shadow: eh = fp16(concat(user, item))  (runs after place;
// eh aliases the then-dead pay region)
// ===========================================================================
__global__ void initH_kernel(const float* __restrict__ user_t,
                             const float* __restrict__ item_t,
                             _Float16* __restrict__ eh) {
    int i = blockIdx.x * blockDim.x + threadIdx.x;
    const int total4 = N_NODES * EMB / 4;
    if (i >= total4) return;
    int fi   = i * 4;
    int node = fi >> 6;
    int off  = fi & 63;
    float4 v;
    if (node < N_USERS)
        v = *(const float4*)(user_t + (size_t)node * EMB + off);
    else
        v = *(const float4*)(item_t + (size_t)(node - N_USERS) * EMB + off);
    h4 h = { (_Float16)v.x, (_Float16)v.y, (_Float16)v.z, (_Float16)v.w };
    *(h4*)(eh + fi) = h;
}

// ===========================================================================
// SpMM core: fp16 gather source (128B/row), fp32 accumulate.
// ===========================================================================
__device__ __forceinline__ float4 row_gather_h(const int*      __restrict__ rp,
                                               const float2*   __restrict__ edges,
                                               const _Float16* __restrict__ xh,
                                               int row, int s) {
    int i   = rp[row];
    int end = rp[row + 1];
    float4 acc = make_float4(0.f, 0.f, 0.f, 0.f);
    for (; i + 3 < end; i += 4) {
        float2 e0 = edges[i];
        float2 e1 = edges[i + 1];
        float2 e2 = edges[i + 2];
        float2 e3 = edges[i + 3];
        h4 a = *(const h4*)(xh + ((size_t)(__float_as_uint(e0.x) & 0x7FFFF) << 6) + (s << 2));
        h4 b = *(const h4*)(xh + ((size_t)(__float_as_uint(e1.x) & 0x7FFFF) << 6) + (s << 2));
        h4 c = *(const h4*)(xh + ((size_t)(__float_as_uint(e2.x) & 0x7FFFF) << 6) + (s << 2));
        h4 d = *(const h4*)(xh + ((size_t)(__float_as_uint(e3.x) & 0x7FFFF) << 6) + (s << 2));
        acc.x += e0.y * (float)a.x + e1.y * (float)b.x + e2.y * (float)c.x + e3.y * (float)d.x;
        acc.y += e0.y * (float)a.y + e1.y * (float)b.y + e2.y * (float)c.y + e3.y * (float)d.y;
        acc.z += e0.y * (float)a.z + e1.y * (float)b.z + e2.y * (float)c.z + e3.y * (float)d.z;
        acc.w += e0.y * (float)a.w + e1.y * (float)b.w + e2.y * (float)c.w + e3.y * (float)d.w;
    }
    for (; i < end; ++i) {
        float2 e0 = edges[i];
        h4 a = *(const h4*)(xh + ((size_t)(__float_as_uint(e0.x) & 0x7FFFF) << 6) + (s << 2));
        acc.x += e0.y * (float)a.x;
        acc.y += e0.y * (float)a.y;
        acc.z += e0.y * (float)a.z;
        acc.w += e0.y * (float)a.w;
    }
    return acc;
}

// layers 1,2: y_h = fp16(A * x_h)
__global__ void spmm_yh_kernel(const int*      __restrict__ rp,
                               const float2*   __restrict__ edges,
                               const _Float16* __restrict__ xh,
                               _Float16*       __restrict__ yh) {
    int t    = blockIdx.x * blockDim.x + threadIdx.x;
    int wid  = t >> 6;
    int lane = t & 63;
    int q    = lane >> 4;
    int s    = lane & 15;
    int row  = (wid << 2) + q;
    if (row >= N_NODES) return;
    float4 acc = row_gather_h(rp, edges, xh, row, s);
    h4 h = { (_Float16)acc.x, (_Float16)acc.y, (_Float16)acc.z, (_Float16)acc.w };
    *(h4*)(yh + (((size_t)row << 6) + (s << 2))) = h;
}

// layer 3 fused final: out = (e_fp32 + y1 + y2 + A*y2) / 4
__global__ void spmm_fin_kernel(const int*      __restrict__ rp,
                                const float2*   __restrict__ edges,
                                const float*    __restrict__ user_t,
                                const float*    __restrict__ item_t,
                                const _Float16* __restrict__ y1h,
                                const _Float16* __restrict__ y2h,
                                float*          __restrict__ out) {
    int t    = blockIdx.x * blockDim.x + threadIdx.x;
    int wid  = t >> 6;
    int lane = t & 63;
    int q    = lane >> 4;
    int s    = lane & 15;
    int row  = (wid << 2) + q;
    if (row >= N_NODES) return;
    float4 acc = row_gather_h(rp, edges, y2h, row, s);
    size_t o = ((size_t)row << 6) + (s << 2);
    float4 ev;
    if (row < N_USERS)
        ev = *(const float4*)(user_t + o);
    else
        ev = *(const float4*)(item_t + o - ((size_t)N_USERS << 6));
    h4 v1 = *(const h4*)(y1h + o);
    h4 v2 = *(const h4*)(y2h + o);
    float4 r;
    r.x = (ev.x + (float)v1.x + (float)v2.x + acc.x) * 0.25f;
    r.y = (ev.y + (float)v1.y + (float)v2.y + acc.y) * 0.25f;
    r.z = (ev.z + (float)v1.z + (float)v2.z + acc.z) * 0.25f;
    r.w = (ev.w + (float)v1.w + (float)v2.w + acc.w) * 0.25f;
    *(float4*)(out + o) = r;
}

// ===========================================================================
// Fallback atomic path (tiny ws only)
// ===========================================================================
__global__ void init_kernel(const float* __restrict__ user_t,
                            const float* __restrict__ item_t,
                            float* __restrict__ out,
                            float* __restrict__ bufA,
                            float* __restrict__ bufB) {
    int i = blockIdx.x * blockDim.x + threadIdx.x;
    const int total4 = N_NODES * EMB / 4;
    if (i >= total4) return;
    int fi   = i * 4;
    int node = fi >> 6;
    int off  = fi & 63;
    float4 v;
    if (node < N_USERS)
        v = *(const float4*)(user_t + (size_t)node * EMB + off);
    else
        v = *(const float4*)(item_t + (size_t)(node - N_USERS) * EMB + off);
    *(float4*)(out  + fi) = v;
    *(float4*)(bufA + fi) = v;
    *(float4*)(bufB + fi) = make_float4(0.f, 0.f, 0.f, 0.f);
}

__global__ void spmm_kernel(const int*   __restrict__ rows,
                            const int*   __restrict__ cols,
                            const float* __restrict__ vals,
                            const float* __restrict__ x,
                            float*       __restrict__ y) {
    int tid  = blockIdx.x * blockDim.x + threadIdx.x;
    int e    = tid >> 6;
    int lane = tid & 63;
    if (e >= NNZ) return;
    atomicAdd(&y[(size_t)rows[e] * EMB + lane], vals[e] * x[(size_t)cols[e] * EMB + lane]);
}

__global__ void acc_zero_kernel(float* __restrict__ out,
                                const float* __restrict__ src,
                                float* __restrict__ zbuf) {
    int i = blockIdx.x * blockDim.x + threadIdx.x;
    const int total4 = N_NODES * EMB / 4;
    if (i >= total4) return;
    int fi = i * 4;
    float4 o = *(float4*)(out + fi);
    float4 s = *(const float4*)(src + fi);
    o.x += s.x; o.y += s.y; o.z += s.z; o.w += s.w;
    *(float4*)(out  + fi) = o;
    *(float4*)(zbuf + fi) = make_float4(0.f, 0.f, 0.f, 0.f);
}

__global__ void final_kernel(float* __restrict__ out,
                             const float* __restrict__ src) {
    int i = blockIdx.x * blockDim.x + threadIdx.x;
    const int total4 = N_NODES * EMB / 4;
    if (i >= total4) return;
    int fi = i * 4;
    float4 o = *(float4*)(out + fi);
    float4 s = *(const float4*)(src + fi);
    o.x = (o.x + s.x) * 0.25f;
    o.y = (o.y + s.y) * 0.25f;
    o.z = (o.z + s.z) * 0.25f;
    o.w = (o.w + s.w) * 0.25f;
    *(float4*)(out + fi) = o;
}

// ===========================================================================
extern "C" void kernel_launch(void* const* d_in, const int* in_sizes, int n_in,
                              void* d_out, int out_size, void* d_ws, size_t ws_size,
                              hipStream_t stream) {
    const float* user_t = (const float*)d_in[0];
    const float* item_t = (const float*)d_in[1];
    const int*   rows   = (const int*)d_in[2];
    const int*   cols   = (const int*)d_in[3];
    const float* vals   = (const float*)d_in[4];
    float* out = (float*)d_out;

    const size_t embh_bytes = (size_t)N_NODES * EMB * 2;          // 38.4 MB
    const size_t emb_bytes  = (size_t)N_NODES * EMB * 4;          // 76.8 MB
    const size_t pay_bytes  = (size_t)NBUCK * SEGCAP * 8;         // 34.8 MB
    const size_t r0_bytes   = (pay_bytes > embh_bytes ? pay_bytes : embh_bytes);
    const size_t edges_bytes = (size_t)NNZ * 8;                   // 32 MB
    const size_t small_bytes = (size_t)(N_NODES + 1) * 4
                             + (size_t)NBUCK * 16 * 4
                             + (size_t)(NBUCK + 1) * 4;
    const int total4    = N_NODES * EMB / 4;
    const int ew_blocks = (total4 + 255) / 256;

    const size_t need_h = r0_bytes + 2 * embh_bytes + edges_bytes + small_bytes; // ~148 MB
    const int spmm_blocks = (int)(((size_t)N_NODES / 4 * 64 + 255) / 256); // 18750

    if (ws_size >= need_h) {
        // ---- fp16-gather tier ----
        char* p = (char*)d_ws;
        char*     region0 = p;            p += r0_bytes;  // pay -> eh (aliased)
        _Float16* y1h     = (_Float16*)p; p += embh_bytes;
        _Float16* y2h     = (_Float16*)p; p += embh_bytes;
        float2*   edges   = (float2*)p;   p += edges_bytes;
        int*      row_ptr = (int*)p;      p += (size_t)(N_NODES + 1) * 4;
        int*      bcnt    = (int*)p;      p += (size_t)NBUCK * 16 * 4;
        int*      bbase   = (int*)p;
        float2*   pay = (float2*)region0;          // dead after place
        _Float16* eh  = (_Float16*)region0;        // built after place

        hipMemsetAsync(bcnt, 0, (size_t)NBUCK * 16 * 4, stream);
        bucket_agg_kernel<<<AGG_BLOCKS, AGG_THR, 0, stream>>>(rows, cols, vals, bcnt, pay);
        bscan_kernel<<<1, 512, 0, stream>>>(bcnt, bbase, row_ptr);
        place_kernel<<<NBUCK, 1024, 0, stream>>>(bcnt, bbase, pay, row_ptr, edges);

        initH_kernel<<<ew_blocks, 256, 0, stream>>>(user_t, item_t, eh);

        spmm_yh_kernel <<<spmm_blocks, 256, 0, stream>>>(row_ptr, edges, eh,  y1h);
        spmm_yh_kernel <<<spmm_blocks, 256, 0, stream>>>(row_ptr, edges, y1h, y2h);
        spmm_fin_kernel<<<spmm_blocks, 256, 0, stream>>>(row_ptr, edges, user_t, item_t,
                                                         y1h, y2h, out);
    } else {
        // ---- tiny-ws fallback ----
        char* p = (char*)d_ws;
        float* bufA = (float*)p; p += emb_bytes;
        float* bufB = (float*)p;
        const int spmmA_blocks = (int)(((size_t)NNZ * 64 + 255) / 256);
        init_kernel<<<ew_blocks, 256, 0, stream>>>(user_t, item_t, out, bufA, bufB);
        spmm_kernel<<<spmmA_blocks, 256, 0, stream>>>(rows, cols, vals, bufA, bufB);
        acc_zero_kernel<<<ew_blocks, 256, 0, stream>>>(out, bufB, bufA);
        spmm_kernel<<<spmmA_blocks, 256, 0, stream>>>(rows, cols, vals, bufB, bufA);
        acc_zero_kernel<<<ew_blocks, 256, 0, stream>>>(out, bufA, bufB);
        spmm_kernel<<<spmmA_blocks, 256, 0, stream>>>(rows, cols, vals, bufA, bufB);
        final_kernel<<<ew_blocks, 256, 0, stream>>>(out, bufB);
    }
}

// Round 12
// 488.620 us; speedup vs baseline: 10.6425x; 1.0300x over previous
//
#include <hip/hip_runtime.h>

#define N_USERS 100000
#define N_ITEMS 200000
#define N_NODES (N_USERS + N_ITEMS)
#define EMB     64
#define NNZ     4000000

// coarse row-buckets: 1200 rows each -> NBUCK = 250 = one bucket per CU
#define BROWS  1200
#define NBUCK  250
#define SCAN_N 512                                         // pow2 >= NBUCK

// block-aggregated binning pass
#define AGG_THR    512
#define AGG_EPT    8
#define AGG_T      (AGG_THR * AGG_EPT)                     // 4096 edges / block
#define AGG_BLOCKS ((NNZ + AGG_T - 1) / AGG_T)             // 977
#define EH_BLOCKS  295                                     // fused eh-copy blocks

// bucket segment capacity (mean fill 16000, sigma ~126 -> +11 sigma headroom)
#define SEGCAP 17408
#define PITER  17                                          // ceil(SEGCAP/1024)

typedef _Float16 h4 __attribute__((ext_vector_type(4)));   // 8B vector of fp16

// NOTE (r3): __builtin_nontemporal_load on gfx950 = last-use/invalidating;
// on dirty lines -> ~35x WRITE amplification. Plain loads only.
// NOTE (r4): per-edge global atomics cost ~32B HBM each. Aggregate in LDS.
// NOTE (r6): gather is DRAM-efficiency bound; only byte reduction helps.
// NOTE (r7): fp16 gather sources halve bytes; absmax unchanged (1.5e-5).
// NOTE (r8): smaller buckets degrade bucket_agg segment writes (sub-line).
// NOTE (r9): LDS fp32 atomicAdd SpMM = 15x SLOWER. Keep CSR + reg accum.
// NOTE (r10): fusing work into place regressed; place is single-round and
// latency-critical. r12 instead backfills bucket_agg's occupancy tail
// (977 blocks @ 3/CU = 1.27 rounds) with the eh table->fp16 copy.
// NOTE (r11): 250x1200 bucket geometry (1 place round) = best build so far.

// ===========================================================================
// CSR build (histogram-free, bucket-segmented)
// ===========================================================================
// pass 1: blocks [0, AGG_BLOCKS): bin 4096 edges/block into coarse buckets
// via LDS counting-sort; one global atomic per (block,bucket); coalesced run
// writes into segments. pk = b(8b)<<23 | rlo(11b)<<12 | lp(12b).
// pay.x packs col(19b) | rlo<<19.
// blocks [AGG_BLOCKS, AGG_BLOCKS+EH_BLOCKS): build fp16 shadow eh
// (fused initH -- fills this kernel's second occupancy round).
__global__ __launch_bounds__(AGG_THR)
void bucket_agg_kernel(const int*   __restrict__ rows,
                       const int*   __restrict__ cols,
                       const float* __restrict__ vals,
                       int*         __restrict__ bcnt,   // [NBUCK*16] zeroed
                       float2*      __restrict__ pay,    // [NBUCK*SEGCAP]
                       const float* __restrict__ user_t,
                       const float* __restrict__ item_t,
                       _Float16*    __restrict__ eh) {
    if (blockIdx.x >= AGG_BLOCKS) {
        // ---- fused eh-copy path (no LDS use) ----
        const int total4 = N_NODES * EMB / 4;
        int idx    = (blockIdx.x - AGG_BLOCKS) * AGG_THR + threadIdx.x;
        int stride = EH_BLOCKS * AGG_THR;
        for (int i = idx; i < total4; i += stride) {
            int fi   = i * 4;
            int node = fi >> 6;
            int off  = fi & 63;
            float4 v;
            if (node < N_USERS)
                v = *(const float4*)(user_t + (size_t)node * EMB + off);
            else
                v = *(const float4*)(item_t + (size_t)(node - N_USERS) * EMB + off);
            h4 h = { (_Float16)v.x, (_Float16)v.y, (_Float16)v.z, (_Float16)v.w };
            *(h4*)(eh + fi) = h;
        }
        return;
    }

    __shared__ int            cntS[SCAN_N];   // counts -> exclusive scan
    __shared__ int            hoff[SCAN_N];   // segment offset per bucket
    __shared__ float2         payS[AGG_T];    // staged (packed col, val)
    __shared__ unsigned short bidS[AGG_T];    // bucket id per staged slot

    int tid  = threadIdx.x;
    int base = blockIdx.x * AGG_T;

    cntS[tid] = 0;
    __syncthreads();

    // phase A: count (keep per-edge bucket/row-lo/local-pos packed in regs)
    unsigned pk[AGG_EPT];
#pragma unroll
    for (int j = 0; j < AGG_EPT; j++) {
        int e = base + j * AGG_THR + tid;
        pk[j] = 0xFFFFFFFFu;
        if (e < NNZ) {
            int r  = rows[e];
            int b  = r / BROWS;                      // 8 bits (const div)
            int rl = r - b * BROWS;                  // 11 bits
            int lp = atomicAdd(&cntS[b], 1);         // <= 4095, 12 bits
            pk[j]  = ((unsigned)b << 23) | ((unsigned)rl << 12) | (unsigned)lp;
        }
    }
    __syncthreads();

    // exclusive scan of cntS (SCAN_N == AGG_THR, one element per thread)
    int v = cntS[tid];
    for (int off = 1; off < SCAN_N; off <<= 1) {
        int t = 0;
        if (tid >= off) t = cntS[tid - off];
        __syncthreads();
        if (tid >= off) cntS[tid] += t;
        __syncthreads();
    }
    int excl = cntS[tid] - v;

    // reserve segment runs (one atomic per non-empty bucket)
    if (tid < NBUCK && v > 0) hoff[tid] = atomicAdd(&bcnt[tid * 16], v);
    __syncthreads();
    cntS[tid] = excl;
    __syncthreads();

    // phase B: stage into LDS at counting-sort position
#pragma unroll
    for (int j = 0; j < AGG_EPT; j++) {
        if (pk[j] != 0xFFFFFFFFu) {
            int e   = base + j * AGG_THR + tid;
            int b   = pk[j] >> 23;
            int rl  = (pk[j] >> 12) & 0x7FF;
            int lp  = pk[j] & 0xFFF;
            int idx = cntS[b] + lp;
            unsigned packed = (unsigned)cols[e] | ((unsigned)rl << 19);
            payS[idx] = make_float2(__uint_as_float(packed), vals[e]);
            bidS[idx] = (unsigned short)b;
        }
    }
    __syncthreads();

    // write-out: contiguous per-bucket runs into fixed segments
    int total = NNZ - base; if (total > AGG_T) total = AGG_T;
    for (int i = tid; i < total; i += AGG_THR) {
        int b   = bidS[i];
        int pos = hoff[b] + (i - cntS[b]);
        if (pos < SEGCAP)   // 11-sigma safety clamp
            pay[(size_t)b * SEGCAP + pos] = payS[i];
    }
}

// tiny pass: exclusive-scan the 250 bucket totals -> bbase; seal row_ptr end.
__global__ void bscan_kernel(const int* __restrict__ bcnt,
                             int* __restrict__ bbase,
                             int* __restrict__ row_ptr) {
    __shared__ int s[512];
    int tid = threadIdx.x;
    int v = 0;
    if (tid < NBUCK) {
        v = bcnt[tid * 16];
        if (v > SEGCAP) v = SEGCAP;
    }
    s[tid] = v;
    __syncthreads();
    for (int off = 1; off < 512; off <<= 1) {
        int t = 0;
        if (tid >= off) t = s[tid - off];
        __syncthreads();
        if (tid >= off) s[tid] += t;
        __syncthreads();
    }
    if (tid < NBUCK) bbase[tid] = s[tid] - v;
    if (tid == 511) bbase[NBUCK] = s[511];
    if (tid == 0)   row_ptr[N_NODES] = NNZ;
}

// pass 2: one block per 1200-row bucket (250 blocks = 1 occupancy round).
// Counting-sort the bucket's segment by row ENTIRELY IN LDS (~148KB), emit
// row_ptr slice, stream sorted run out -> full-line coalesced stores.
__global__ __launch_bounds__(1024)
void place_kernel(const int*    __restrict__ bcnt,
                  const int*    __restrict__ bbase,
                  const float2* __restrict__ pay,
                  int*          __restrict__ row_ptr,
                  float2*       __restrict__ edges) {
    __shared__ float2 payS[SEGCAP];   // 139264 B
    __shared__ int    cntS[2048];     //   8192 B (1200 used, rest zero)
    __shared__ int    sS[1024];       //   4096 B
    int b   = blockIdx.x;
    int tid = threadIdx.x;
    int run = bcnt[b * 16]; if (run > SEGCAP) run = SEGCAP;
    int beg = bbase[b];
    const float2* seg = pay + (size_t)b * SEGCAP;

    cntS[tid]        = 0;
    cntS[tid + 1024] = 0;
    __syncthreads();

    // phase A: pull edges into registers (fully unrolled -> static indexing),
    // histogram rows; atomic return value = within-row slot.
    unsigned eu[PITER]; float ev[PITER]; int elp[PITER];
#pragma unroll
    for (int j = 0; j < PITER; j++) {
        int i = j * 1024 + tid;
        eu[j] = 0xFFFFFFFFu;
        if (i < run) {
            float2 p = seg[i];
            unsigned u = __float_as_uint(p.x);
            eu[j] = u;
            ev[j] = p.y;
            elp[j] = atomicAdd(&cntS[u >> 19], 1);
        }
    }
    __syncthreads();

    // scan of 1200 row-counts: 2 slots/thread, Hillis-Steele over pair-sums
    int v0 = cntS[2 * tid];
    int v1 = cntS[2 * tid + 1];
    int pv = v0 + v1;
    sS[tid] = pv;
    __syncthreads();
    for (int off = 1; off < 1024; off <<= 1) {
        int t = 0;
        if (tid >= off) t = sS[tid - off];
        __syncthreads();
        if (tid >= off) sS[tid] += t;
        __syncthreads();
    }
    int excl = sS[tid] - pv;
    cntS[2 * tid]     = excl + v0;         // inclusive at slot 2t
    cntS[2 * tid + 1] = excl + v0 + v1;    // inclusive at slot 2t+1
    __syncthreads();

    // emit row_ptr slice (coalesced; 1200 rows, 2 iterations)
    int r0 = b * BROWS;
#pragma unroll
    for (int j = 0; j < 2; j++) {
        int lr = j * 1024 + tid;
        if (lr < BROWS)
            row_ptr[r0 + lr] = beg + (lr ? cntS[lr - 1] : 0);
    }

    // phase B: scatter into LDS at final sorted position
#pragma unroll
    for (int j = 0; j < PITER; j++) {
        if (eu[j] != 0xFFFFFFFFu) {
            int r    = (int)(eu[j] >> 19);
            int base = (r == 0) ? 0 : cntS[r - 1];
            payS[base + elp[j]] = make_float2(__uint_as_float(eu[j] & 0x7FFFFu), ev[j]);
        }
    }
    __syncthreads();

    // phase C: stream out sequentially — full-line coalesced stores
    for (int i = tid; i < run; i += 1024) {
        edges[beg + i] = payS[i];
    }
}

// ===========================================================================
// SpMM core: fp16 gather source (128B/row), fp32 accumulate.
// ===========================================================================
__device__ __forceinline__ float4 row_gather_h(const int*      __restrict__ rp,
                                               const float2*   __restrict__ edges,
                                               const _Float16* __restrict__ xh,
                                               int row, int s) {
    int i   = rp[row];
    int end = rp[row + 1];
    float4 acc = make_float4(0.f, 0.f, 0.f, 0.f);
    for (; i + 3 < end; i += 4) {
        float2 e0 = edges[i];
        float2 e1 = edges[i + 1];
        float2 e2 = edges[i + 2];
        float2 e3 = edges[i + 3];
        h4 a = *(const h4*)(xh + ((size_t)(__float_as_uint(e0.x) & 0x7FFFF) << 6) + (s << 2));
        h4 b = *(const h4*)(xh + ((size_t)(__float_as_uint(e1.x) & 0x7FFFF) << 6) + (s << 2));
        h4 c = *(const h4*)(xh + ((size_t)(__float_as_uint(e2.x) & 0x7FFFF) << 6) + (s << 2));
        h4 d = *(const h4*)(xh + ((size_t)(__float_as_uint(e3.x) & 0x7FFFF) << 6) + (s << 2));
        acc.x += e0.y * (float)a.x + e1.y * (float)b.x + e2.y * (float)c.x + e3.y * (float)d.x;
        acc.y += e0.y * (float)a.y + e1.y * (float)b.y + e2.y * (float)c.y + e3.y * (float)d.y;
        acc.z += e0.y * (float)a.z + e1.y * (float)b.z + e2.y * (float)c.z + e3.y * (float)d.z;
        acc.w += e0.y * (float)a.w + e1.y * (float)b.w + e2.y * (float)c.w + e3.y * (float)d.w;
    }
    for (; i < end; ++i) {
        float2 e0 = edges[i];
        h4 a = *(const h4*)(xh + ((size_t)(__float_as_uint(e0.x) & 0x7FFFF) << 6) + (s << 2));
        acc.x += e0.y * (float)a.x;
        acc.y += e0.y * (float)a.y;
        acc.z += e0.y * (float)a.z;
        acc.w += e0.y * (float)a.w;
    }
    return acc;
}

// layers 1,2: y_h = fp16(A * x_h)
__global__ void spmm_yh_kernel(const int*      __restrict__ rp,
                               const float2*   __restrict__ edges,
                               const _Float16* __restrict__ xh,
                               _Float16*       __restrict__ yh) {
    int t    = blockIdx.x * blockDim.x + threadIdx.x;
    int wid  = t >> 6;
    int lane = t & 63;
    int q    = lane >> 4;
    int s    = lane & 15;
    int row  = (wid << 2) + q;
    if (row >= N_NODES) return;
    float4 acc = row_gather_h(rp, edges, xh, row, s);
    h4 h = { (_Float16)acc.x, (_Float16)acc.y, (_Float16)acc.z, (_Float16)acc.w };
    *(h4*)(yh + (((size_t)row << 6) + (s << 2))) = h;
}

// layer 3 fused final: out = (e + y1 + y2 + A*y2) / 4, all fp16 sources
// (e from eh: |e|<=0.0077 * 2^-11 / 4 ~= 1e-6 added error -- negligible
// against the current 1.5e-5 absmax; saves the 75MB fp32 table stream).
__global__ void spmm_fin_kernel(const int*      __restrict__ rp,
                                const float2*   __restrict__ edges,
                                const _Float16* __restrict__ eh,
                                const _Float16* __restrict__ y1h,
                                const _Float16* __restrict__ y2h,
                                float*          __restrict__ out) {
    int t    = blockIdx.x * blockDim.x + threadIdx.x;
    int wid  = t >> 6;
    int lane = t & 63;
    int q    = lane >> 4;
    int s    = lane & 15;
    int row  = (wid << 2) + q;
    if (row >= N_NODES) return;
    float4 acc = row_gather_h(rp, edges, y2h, row, s);
    size_t o = ((size_t)row << 6) + (s << 2);
    h4 e0 = *(const h4*)(eh  + o);
    h4 v1 = *(const h4*)(y1h + o);
    h4 v2 = *(const h4*)(y2h + o);
    float4 r;
    r.x = ((float)e0.x + (float)v1.x + (float)v2.x + acc.x) * 0.25f;
    r.y = ((float)e0.y + (float)v1.y + (float)v2.y + acc.y) * 0.25f;
    r.z = ((float)e0.z + (float)v1.z + (float)v2.z + acc.z) * 0.25f;
    r.w = ((float)e0.w + (float)v1.w + (float)v2.w + acc.w) * 0.25f;
    *(float4*)(out + o) = r;
}

// ===========================================================================
// Fallback atomic path (tiny ws only)
// ===========================================================================
__global__ void init_kernel(const float* __restrict__ user_t,
                            const float* __restrict__ item_t,
                            float* __restrict__ out,
                            float* __restrict__ bufA,
                            float* __restrict__ bufB) {
    int i = blockIdx.x * blockDim.x + threadIdx.x;
    const int total4 = N_NODES * EMB / 4;
    if (i >= total4) return;
    int fi   = i * 4;
    int node = fi >> 6;
    int off  = fi & 63;
    float4 v;
    if (node < N_USERS)
        v = *(const float4*)(user_t + (size_t)node * EMB + off);
    else
        v = *(const float4*)(item_t + (size_t)(node - N_USERS) * EMB + off);
    *(float4*)(out  + fi) = v;
    *(float4*)(bufA + fi) = v;
    *(float4*)(bufB + fi) = make_float4(0.f, 0.f, 0.f, 0.f);
}

__global__ void spmm_kernel(const int*   __restrict__ rows,
                            const int*   __restrict__ cols,
                            const float* __restrict__ vals,
                            const float* __restrict__ x,
                            float*       __restrict__ y) {
    int tid  = blockIdx.x * blockDim.x + threadIdx.x;
    int e    = tid >> 6;
    int lane = tid & 63;
    if (e >= NNZ) return;
    atomicAdd(&y[(size_t)rows[e] * EMB + lane], vals[e] * x[(size_t)cols[e] * EMB + lane]);
}

__global__ void acc_zero_kernel(float* __restrict__ out,
                                const float* __restrict__ src,
                                float* __restrict__ zbuf) {
    int i = blockIdx.x * blockDim.x + threadIdx.x;
    const int total4 = N_NODES * EMB / 4;
    if (i >= total4) return;
    int fi = i * 4;
    float4 o = *(float4*)(out + fi);
    float4 s = *(const float4*)(src + fi);
    o.x += s.x; o.y += s.y; o.z += s.z; o.w += s.w;
    *(float4*)(out  + fi) = o;
    *(float4*)(zbuf + fi) = make_float4(0.f, 0.f, 0.f, 0.f);
}

__global__ void final_kernel(float* __restrict__ out,
                             const float* __restrict__ src) {
    int i = blockIdx.x * blockDim.x + threadIdx.x;
    const int total4 = N_NODES * EMB / 4;
    if (i >= total4) return;
    int fi = i * 4;
    float4 o = *(float4*)(out + fi);
    float4 s = *(const float4*)(src + fi);
    o.x = (o.x + s.x) * 0.25f;
    o.y = (o.y + s.y) * 0.25f;
    o.z = (o.z + s.z) * 0.25f;
    o.w = (o.w + s.w) * 0.25f;
    *(float4*)(out + fi) = o;
}

// ===========================================================================
extern "C" void kernel_launch(void* const* d_in, const int* in_sizes, int n_in,
                              void* d_out, int out_size, void* d_ws, size_t ws_size,
                              hipStream_t stream) {
    const float* user_t = (const float*)d_in[0];
    const float* item_t = (const float*)d_in[1];
    const int*   rows   = (const int*)d_in[2];
    const int*   cols   = (const int*)d_in[3];
    const float* vals   = (const float*)d_in[4];
    float* out = (float*)d_out;

    const size_t embh_bytes = (size_t)N_NODES * EMB * 2;          // 38.4 MB
    const size_t emb_bytes  = (size_t)N_NODES * EMB * 4;          // 76.8 MB
    const size_t pay_bytes  = (size_t)NBUCK * SEGCAP * 8;         // 34.8 MB
    const size_t edges_bytes = (size_t)NNZ * 8;                   // 32 MB
    const size_t small_bytes = (size_t)(N_NODES + 1) * 4
                             + (size_t)NBUCK * 16 * 4
                             + (size_t)(NBUCK + 1) * 4;
    const int total4    = N_NODES * EMB / 4;
    const int ew_blocks = (total4 + 255) / 256;

    // eh de-aliased from pay (r12): enables fused eh-copy inside bucket_agg
    const size_t need_h = pay_bytes + 3 * embh_bytes + edges_bytes + small_bytes; // ~183 MB
    const int spmm_blocks = (int)(((size_t)N_NODES / 4 * 64 + 255) / 256); // 18750

    if (ws_size >= need_h) {
        // ---- fp16-gather tier ----
        char* p = (char*)d_ws;
        float2*   pay     = (float2*)p;   p += pay_bytes;
        _Float16* eh      = (_Float16*)p; p += embh_bytes;
        _Float16* y1h     = (_Float16*)p; p += embh_bytes;
        _Float16* y2h     = (_Float16*)p; p += embh_bytes;
        float2*   edges   = (float2*)p;   p += edges_bytes;
        int*      row_ptr = (int*)p;      p += (size_t)(N_NODES + 1) * 4;
        int*      bcnt    = (int*)p;      p += (size_t)NBUCK * 16 * 4;
        int*      bbase   = (int*)p;

        hipMemsetAsync(bcnt, 0, (size_t)NBUCK * 16 * 4, stream);
        bucket_agg_kernel<<<AGG_BLOCKS + EH_BLOCKS, AGG_THR, 0, stream>>>(
            rows, cols, vals, bcnt, pay, user_t, item_t, eh);
        bscan_kernel<<<1, 512, 0, stream>>>(bcnt, bbase, row_ptr);
        place_kernel<<<NBUCK, 1024, 0, stream>>>(bcnt, bbase, pay, row_ptr, edges);

        spmm_yh_kernel <<<spmm_blocks, 256, 0, stream>>>(row_ptr, edges, eh,  y1h);
        spmm_yh_kernel <<<spmm_blocks, 256, 0, stream>>>(row_ptr, edges, y1h, y2h);
        spmm_fin_kernel<<<spmm_blocks, 256, 0, stream>>>(row_ptr, edges, eh,
                                                         y1h, y2h, out);
    } else {
        // ---- tiny-ws fallback ----
        char* p = (char*)d_ws;
        float* bufA = (float*)p; p += emb_bytes;
        float* bufB = (float*)p;
        const int spmmA_blocks = (int)(((size_t)NNZ * 64 + 255) / 256);
        init_kernel<<<ew_blocks, 256, 0, stream>>>(user_t, item_t, out, bufA, bufB);
        spmm_kernel<<<spmmA_blocks, 256, 0, stream>>>(rows, cols, vals, bufA, bufB);
        acc_zero_kernel<<<ew_blocks, 256, 0, stream>>>(out, bufB, bufA);
        spmm_kernel<<<spmmA_blocks, 256, 0, stream>>>(rows, cols, vals, bufB, bufA);
        acc_zero_kernel<<<ew_blocks, 256, 0, stream>>>(out, bufA, bufB);
        spmm_kernel<<<spmmA_blocks, 256, 0, stream>>>(rows, cols, vals, bufA, bufB);
        final_kernel<<<ew_blocks, 256, 0, stream>>>(out, bufB);
    }
}

// Round 13
// 486.984 us; speedup vs baseline: 10.6782x; 1.0034x over previous
//
#include <hip/hip_runtime.h>

#define N_USERS 100000
#define N_ITEMS 200000
#define N_NODES (N_USERS + N_ITEMS)
#define EMB     64
#define NNZ     4000000

// coarse row-buckets: 1200 rows each -> NBUCK = 250 = one bucket per CU
#define BROWS  1200
#define NBUCK  250
#define SCAN_N 512                                         // pow2 >= NBUCK

// block-aggregated binning pass
#define AGG_THR    512
#define AGG_EPT    8
#define AGG_T      (AGG_THR * AGG_EPT)                     // 4096 edges / block
#define AGG_BLOCKS ((NNZ + AGG_T - 1) / AGG_T)             // 977
#define EH_BLOCKS  295                                     // fused eh-copy blocks

// bucket segment capacity (mean fill 16000, sigma ~126 -> +11 sigma headroom)
#define SEGCAP 17408
#define PITER  17                                          // ceil(SEGCAP/1024)

typedef _Float16 h4 __attribute__((ext_vector_type(4)));   // 8B vector of fp16
typedef float    fv2 __attribute__((ext_vector_type(2)));

// fp8 gather shadows are stored scaled by 256 (values ~1e-3 would be e4m3
// subnormals unscaled; x256 puts them in the normal range, max |y3|*256~123
// < 448). Accumulators over scaled operands carry the 256 factor; divide once.
#define YSCALE     256.0f
#define YSCALE_INV 0.00390625f

// NOTE (r3): __builtin_nontemporal_load on gfx950 = last-use/invalidating;
// on dirty lines -> ~35x WRITE amplification. Plain loads only.
// NOTE (r4): per-edge global atomics cost ~32B HBM each. Aggregate in LDS.
// NOTE (r6): gather is DRAM-efficiency bound; only byte reduction helps.
// NOTE (r7): fp16 gather sources halve bytes; absmax unchanged (1.5e-5).
// NOTE (r8): smaller buckets degrade bucket_agg segment writes (sub-line).
// NOTE (r9): LDS fp32 atomicAdd SpMM = 15x SLOWER. Keep CSR + reg accum.
// NOTE (r10): fusing work into place regressed; place is single-round.
// NOTE (r11): 250x1200 bucket geometry (1 place round) = best build.
// NOTE (r12): eh-copy fused into bucket_agg's occupancy tail; fin reads eh.
// NOTE (r13): fp8 e4m3 shadows (y1q,y2q) for the GATHER operand only --
// 64B row = 1 cache line, halves gather traffic. LINEAR terms stay fp16
// (fp8 linear would put ~1e-4 directly on out's max-norm).

// ---------------------------------------------------------------------------
// fp8 e4m3 pack/unpack (hw cvt on gfx950; guarded software fallback)
// ---------------------------------------------------------------------------
#if defined(__has_builtin)
#if __has_builtin(__builtin_amdgcn_cvt_pk_f32_fp8) && __has_builtin(__builtin_amdgcn_cvt_pk_fp8_f32)
#define HAVE_HW_FP8 1
#endif
#endif

__device__ __forceinline__ float4 fp8x4_to_f4(unsigned int w) {
#ifdef HAVE_HW_FP8
    fv2 lo = __builtin_amdgcn_cvt_pk_f32_fp8(w, false);
    fv2 hi = __builtin_amdgcn_cvt_pk_f32_fp8(w, true);
    return make_float4(lo.x, lo.y, hi.x, hi.y);
#else
    float r[4];
#pragma unroll
    for (int i = 0; i < 4; i++) {
        unsigned b  = (w >> (8 * i)) & 0xFF;
        unsigned em = b & 0x7F;
        float m;
        if (em >= 0x08) m = __uint_as_float((((em >> 3) + 120u) << 23) | ((em & 7u) << 20));
        else            m = (float)em * 0.001953125f;     // em * 2^-9
        r[i] = (b & 0x80) ? -m : m;
    }
    return make_float4(r[0], r[1], r[2], r[3]);
#endif
}

__device__ __forceinline__ unsigned int f4_to_fp8x4(float4 v) {
#ifdef HAVE_HW_FP8
    unsigned int w = __builtin_amdgcn_cvt_pk_fp8_f32(v.x, v.y, 0u, false);
    w = __builtin_amdgcn_cvt_pk_fp8_f32(v.z, v.w, w, true);
    return w;
#else
    float in[4] = {v.x, v.y, v.z, v.w};
    unsigned int w = 0;
#pragma unroll
    for (int i = 0; i < 4; i++) {
        float x = in[i];
        unsigned s = (__float_as_uint(x) >> 31) << 7;
        float ax = fabsf(x);
        unsigned b;
        if (ax < 0.015625f) {
            int q = (int)(ax * 512.0f + 0.5f);            // round to 2^-9 steps
            b = (q <= 7) ? (unsigned)q : 8u;
        } else {
            if (ax > 448.0f) ax = 448.0f;
            unsigned fb   = __float_as_uint(ax);
            int      e32  = (int)(fb >> 23) - 127;
            unsigned man  = ((fb & 0x7FFFFFu) + 0x80000u) >> 20;  // round
            int      e8   = e32 + 7;
            if (man == 8) { man = 0; e8++; }
            if (e8 > 15)  { e8 = 15; man = 6; }
            b = ((unsigned)e8 << 3) | man;
        }
        w |= (b | s) << (8 * i);
    }
    return w;
#endif
}

// ===========================================================================
// CSR build (histogram-free, bucket-segmented)
// ===========================================================================
// pass 1: blocks [0, AGG_BLOCKS): bin 4096 edges/block into coarse buckets
// via LDS counting-sort; one global atomic per (block,bucket); coalesced run
// writes into segments. pk = b(8b)<<23 | rlo(11b)<<12 | lp(12b).
// pay.x packs col(19b) | rlo<<19.
// blocks [AGG_BLOCKS, AGG_BLOCKS+EH_BLOCKS): build fp16 shadow eh.
__global__ __launch_bounds__(AGG_THR)
void bucket_agg_kernel(const int*   __restrict__ rows,
                       const int*   __restrict__ cols,
                       const float* __restrict__ vals,
                       int*         __restrict__ bcnt,   // [NBUCK*16] zeroed
                       float2*      __restrict__ pay,    // [NBUCK*SEGCAP]
                       const float* __restrict__ user_t,
                       const float* __restrict__ item_t,
                       _Float16*    __restrict__ eh) {
    if (blockIdx.x >= AGG_BLOCKS) {
        // ---- fused eh-copy path (no LDS use) ----
        const int total4 = N_NODES * EMB / 4;
        int idx    = (blockIdx.x - AGG_BLOCKS) * AGG_THR + threadIdx.x;
        int stride = EH_BLOCKS * AGG_THR;
        for (int i = idx; i < total4; i += stride) {
            int fi   = i * 4;
            int node = fi >> 6;
            int off  = fi & 63;
            float4 v;
            if (node < N_USERS)
                v = *(const float4*)(user_t + (size_t)node * EMB + off);
            else
                v = *(const float4*)(item_t + (size_t)(node - N_USERS) * EMB + off);
            h4 h = { (_Float16)v.x, (_Float16)v.y, (_Float16)v.z, (_Float16)v.w };
            *(h4*)(eh + fi) = h;
        }
        return;
    }

    __shared__ int            cntS[SCAN_N];   // counts -> exclusive scan
    __shared__ int            hoff[SCAN_N];   // segment offset per bucket
    __shared__ float2         payS[AGG_T];    // staged (packed col, val)
    __shared__ unsigned short bidS[AGG_T];    // bucket id per staged slot

    int tid  = threadIdx.x;
    int base = blockIdx.x * AGG_T;

    cntS[tid] = 0;
    __syncthreads();

    // phase A: count (keep per-edge bucket/row-lo/local-pos packed in regs)
    unsigned pk[AGG_EPT];
#pragma unroll
    for (int j = 0; j < AGG_EPT; j++) {
        int e = base + j * AGG_THR + tid;
        pk[j] = 0xFFFFFFFFu;
        if (e < NNZ) {
            int r  = rows[e];
            int b  = r / BROWS;                      // 8 bits (const div)
            int rl = r - b * BROWS;                  // 11 bits
            int lp = atomicAdd(&cntS[b], 1);         // <= 4095, 12 bits
            pk[j]  = ((unsigned)b << 23) | ((unsigned)rl << 12) | (unsigned)lp;
        }
    }
    __syncthreads();

    // exclusive scan of cntS (SCAN_N == AGG_THR, one element per thread)
    int v = cntS[tid];
    for (int off = 1; off < SCAN_N; off <<= 1) {
        int t = 0;
        if (tid >= off) t = cntS[tid - off];
        __syncthreads();
        if (tid >= off) cntS[tid] += t;
        __syncthreads();
    }
    int excl = cntS[tid] - v;

    // reserve segment runs (one atomic per non-empty bucket)
    if (tid < NBUCK && v > 0) hoff[tid] = atomicAdd(&bcnt[tid * 16], v);
    __syncthreads();
    cntS[tid] = excl;
    __syncthreads();

    // phase B: stage into LDS at counting-sort position
#pragma unroll
    for (int j = 0; j < AGG_EPT; j++) {
        if (pk[j] != 0xFFFFFFFFu) {
            int e   = base + j * AGG_THR + tid;
            int b   = pk[j] >> 23;
            int rl  = (pk[j] >> 12) & 0x7FF;
            int lp  = pk[j] & 0xFFF;
            int idx = cntS[b] + lp;
            unsigned packed = (unsigned)cols[e] | ((unsigned)rl << 19);
            payS[idx] = make_float2(__uint_as_float(packed), vals[e]);
            bidS[idx] = (unsigned short)b;
        }
    }
    __syncthreads();

    // write-out: contiguous per-bucket runs into fixed segments
    int total = NNZ - base; if (total > AGG_T) total = AGG_T;
    for (int i = tid; i < total; i += AGG_THR) {
        int b   = bidS[i];
        int pos = hoff[b] + (i - cntS[b]);
        if (pos < SEGCAP)   // 11-sigma safety clamp
            pay[(size_t)b * SEGCAP + pos] = payS[i];
    }
}

// tiny pass: exclusive-scan the 250 bucket totals -> bbase; seal row_ptr end.
__global__ void bscan_kernel(const int* __restrict__ bcnt,
                             int* __restrict__ bbase,
                             int* __restrict__ row_ptr) {
    __shared__ int s[512];
    int tid = threadIdx.x;
    int v = 0;
    if (tid < NBUCK) {
        v = bcnt[tid * 16];
        if (v > SEGCAP) v = SEGCAP;
    }
    s[tid] = v;
    __syncthreads();
    for (int off = 1; off < 512; off <<= 1) {
        int t = 0;
        if (tid >= off) t = s[tid - off];
        __syncthreads();
        if (tid >= off) s[tid] += t;
        __syncthreads();
    }
    if (tid < NBUCK) bbase[tid] = s[tid] - v;
    if (tid == 511) bbase[NBUCK] = s[511];
    if (tid == 0)   row_ptr[N_NODES] = NNZ;
}

// pass 2: one block per 1200-row bucket (250 blocks = 1 occupancy round).
// Counting-sort the bucket's segment by row ENTIRELY IN LDS (~148KB), emit
// row_ptr slice, stream sorted run out -> full-line coalesced stores.
__global__ __launch_bounds__(1024)
void place_kernel(const int*    __restrict__ bcnt,
                  const int*    __restrict__ bbase,
                  const float2* __restrict__ pay,
                  int*          __restrict__ row_ptr,
                  float2*       __restrict__ edges) {
    __shared__ float2 payS[SEGCAP];   // 139264 B
    __shared__ int    cntS[2048];     //   8192 B (1200 used, rest zero)
    __shared__ int    sS[1024];       //   4096 B
    int b   = blockIdx.x;
    int tid = threadIdx.x;
    int run = bcnt[b * 16]; if (run > SEGCAP) run = SEGCAP;
    int beg = bbase[b];
    const float2* seg = pay + (size_t)b * SEGCAP;

    cntS[tid]        = 0;
    cntS[tid + 1024] = 0;
    __syncthreads();

    // phase A: pull edges into registers (fully unrolled -> static indexing),
    // histogram rows; atomic return value = within-row slot.
    unsigned eu[PITER]; float ev[PITER]; int elp[PITER];
#pragma unroll
    for (int j = 0; j < PITER; j++) {
        int i = j * 1024 + tid;
        eu[j] = 0xFFFFFFFFu;
        if (i < run) {
            float2 p = seg[i];
            unsigned u = __float_as_uint(p.x);
            eu[j] = u;
            ev[j] = p.y;
            elp[j] = atomicAdd(&cntS[u >> 19], 1);
        }
    }
    __syncthreads();

    // scan of 1200 row-counts: 2 slots/thread, Hillis-Steele over pair-sums
    int v0 = cntS[2 * tid];
    int v1 = cntS[2 * tid + 1];
    int pv = v0 + v1;
    sS[tid] = pv;
    __syncthreads();
    for (int off = 1; off < 1024; off <<= 1) {
        int t = 0;
        if (tid >= off) t = sS[tid - off];
        __syncthreads();
        if (tid >= off) sS[tid] += t;
        __syncthreads();
    }
    int excl = sS[tid] - pv;
    cntS[2 * tid]     = excl + v0;         // inclusive at slot 2t
    cntS[2 * tid + 1] = excl + v0 + v1;    // inclusive at slot 2t+1
    __syncthreads();

    // emit row_ptr slice (coalesced; 1200 rows, 2 iterations)
    int r0 = b * BROWS;
#pragma unroll
    for (int j = 0; j < 2; j++) {
        int lr = j * 1024 + tid;
        if (lr < BROWS)
            row_ptr[r0 + lr] = beg + (lr ? cntS[lr - 1] : 0);
    }

    // phase B: scatter into LDS at final sorted position
#pragma unroll
    for (int j = 0; j < PITER; j++) {
        if (eu[j] != 0xFFFFFFFFu) {
            int r    = (int)(eu[j] >> 19);
            int base = (r == 0) ? 0 : cntS[r - 1];
            payS[base + elp[j]] = make_float2(__uint_as_float(eu[j] & 0x7FFFFu), ev[j]);
        }
    }
    __syncthreads();

    // phase C: stream out sequentially — full-line coalesced stores
    for (int i = tid; i < run; i += 1024) {
        edges[beg + i] = payS[i];
    }
}

// ===========================================================================
// SpMM cores
// ===========================================================================
// fp16 gather (128B/row) — used for layer 1 (x = eh, larger magnitudes)
__device__ __forceinline__ float4 row_gather_h(const int*      __restrict__ rp,
                                               const float2*   __restrict__ edges,
                                               const _Float16* __restrict__ xh,
                                               int row, int s) {
    int i   = rp[row];
    int end = rp[row + 1];
    float4 acc = make_float4(0.f, 0.f, 0.f, 0.f);
    for (; i + 3 < end; i += 4) {
        float2 e0 = edges[i];
        float2 e1 = edges[i + 1];
        float2 e2 = edges[i + 2];
        float2 e3 = edges[i + 3];
        h4 a = *(const h4*)(xh + ((size_t)(__float_as_uint(e0.x) & 0x7FFFF) << 6) + (s << 2));
        h4 b = *(const h4*)(xh + ((size_t)(__float_as_uint(e1.x) & 0x7FFFF) << 6) + (s << 2));
        h4 c = *(const h4*)(xh + ((size_t)(__float_as_uint(e2.x) & 0x7FFFF) << 6) + (s << 2));
        h4 d = *(const h4*)(xh + ((size_t)(__float_as_uint(e3.x) & 0x7FFFF) << 6) + (s << 2));
        acc.x += e0.y * (float)a.x + e1.y * (float)b.x + e2.y * (float)c.x + e3.y * (float)d.x;
        acc.y += e0.y * (float)a.y + e1.y * (float)b.y + e2.y * (float)c.y + e3.y * (float)d.y;
        acc.z += e0.y * (float)a.z + e1.y * (float)b.z + e2.y * (float)c.z + e3.y * (float)d.z;
        acc.w += e0.y * (float)a.w + e1.y * (float)b.w + e2.y * (float)c.w + e3.y * (float)d.w;
    }
    for (; i < end; ++i) {
        float2 e0 = edges[i];
        h4 a = *(const h4*)(xh + ((size_t)(__float_as_uint(e0.x) & 0x7FFFF) << 6) + (s << 2));
        acc.x += e0.y * (float)a.x;
        acc.y += e0.y * (float)a.y;
        acc.z += e0.y * (float)a.z;
        acc.w += e0.y * (float)a.w;
    }
    return acc;
}

// fp8 gather (64B/row = ONE cache line) — x stored scaled by 256;
// returned acc carries the 256 factor.
__device__ __forceinline__ float4 row_gather_q(const int*          __restrict__ rp,
                                               const float2*       __restrict__ edges,
                                               const unsigned int* __restrict__ xq,
                                               int row, int s) {
    int i   = rp[row];
    int end = rp[row + 1];
    float4 acc = make_float4(0.f, 0.f, 0.f, 0.f);
    for (; i + 3 < end; i += 4) {
        float2 e0 = edges[i];
        float2 e1 = edges[i + 1];
        float2 e2 = edges[i + 2];
        float2 e3 = edges[i + 3];
        float4 a = fp8x4_to_f4(xq[((size_t)(__float_as_uint(e0.x) & 0x7FFFF) << 4) + s]);
        float4 b = fp8x4_to_f4(xq[((size_t)(__float_as_uint(e1.x) & 0x7FFFF) << 4) + s]);
        float4 c = fp8x4_to_f4(xq[((size_t)(__float_as_uint(e2.x) & 0x7FFFF) << 4) + s]);
        float4 d = fp8x4_to_f4(xq[((size_t)(__float_as_uint(e3.x) & 0x7FFFF) << 4) + s]);
        acc.x += e0.y * a.x + e1.y * b.x + e2.y * c.x + e3.y * d.x;
        acc.y += e0.y * a.y + e1.y * b.y + e2.y * c.y + e3.y * d.y;
        acc.z += e0.y * a.z + e1.y * b.z + e2.y * c.z + e3.y * d.z;
        acc.w += e0.y * a.w + e1.y * b.w + e2.y * c.w + e3.y * d.w;
    }
    for (; i < end; ++i) {
        float2 e0 = edges[i];
        float4 a = fp8x4_to_f4(xq[((size_t)(__float_as_uint(e0.x) & 0x7FFFF) << 4) + s]);
        acc.x += e0.y * a.x;
        acc.y += e0.y * a.y;
        acc.z += e0.y * a.z;
        acc.w += e0.y * a.w;
    }
    return acc;
}

// layer 1: y1 = A * eh (fp16 gather); write y1h (fp16) + y1q (fp8, x256)
__global__ void spmm_y1_kernel(const int*      __restrict__ rp,
                               const float2*   __restrict__ edges,
                               const _Float16* __restrict__ eh,
                               _Float16*       __restrict__ y1h,
                               unsigned int*   __restrict__ y1q) {
    int t    = blockIdx.x * blockDim.x + threadIdx.x;
    int wid  = t >> 6;
    int lane = t & 63;
    int q    = lane >> 4;
    int s    = lane & 15;
    int row  = (wid << 2) + q;
    if (row >= N_NODES) return;
    float4 acc = row_gather_h(rp, edges, eh, row, s);
    size_t o = ((size_t)row << 6) + (s << 2);
    h4 h = { (_Float16)acc.x, (_Float16)acc.y, (_Float16)acc.z, (_Float16)acc.w };
    *(h4*)(y1h + o) = h;
    float4 sc = make_float4(acc.x * YSCALE, acc.y * YSCALE, acc.z * YSCALE, acc.w * YSCALE);
    y1q[((size_t)row << 4) + s] = f4_to_fp8x4(sc);
}

// layer 2: y2 = A * y1 (fp8 gather, acc carries x256); write y2h + y2q
__global__ void spmm_y2_kernel(const int*          __restrict__ rp,
                               const float2*       __restrict__ edges,
                               const unsigned int* __restrict__ y1q,
                               _Float16*           __restrict__ y2h,
                               unsigned int*       __restrict__ y2q) {
    int t    = blockIdx.x * blockDim.x + threadIdx.x;
    int wid  = t >> 6;
    int lane = t & 63;
    int q    = lane >> 4;
    int s    = lane & 15;
    int row  = (wid << 2) + q;
    if (row >= N_NODES) return;
    float4 acc = row_gather_q(rp, edges, y1q, row, s);   // = y2 * 256
    size_t o = ((size_t)row << 6) + (s << 2);
    h4 h = { (_Float16)(acc.x * YSCALE_INV), (_Float16)(acc.y * YSCALE_INV),
             (_Float16)(acc.z * YSCALE_INV), (_Float16)(acc.w * YSCALE_INV) };
    *(h4*)(y2h + o) = h;
    y2q[((size_t)row << 4) + s] = f4_to_fp8x4(acc);      // already scaled
}

// layer 3 fused final: out = (e + y1 + y2 + A*y2) / 4
// gather from y2q (fp8, acc = y3*256); linear terms fp16.
__global__ void spmm_fin_kernel(const int*          __restrict__ rp,
                                const float2*       __restrict__ edges,
                                const _Float16*     __restrict__ eh,
                                const _Float16*     __restrict__ y1h,
                                const _Float16*     __restrict__ y2h,
                                const unsigned int* __restrict__ y2q,
                                float*              __restrict__ out) {
    int t    = blockIdx.x * blockDim.x + threadIdx.x;
    int wid  = t >> 6;
    int lane = t & 63;
    int q    = lane >> 4;
    int s    = lane & 15;
    int row  = (wid << 2) + q;
    if (row >= N_NODES) return;
    float4 acc = row_gather_q(rp, edges, y2q, row, s);   // = y3 * 256
    size_t o = ((size_t)row << 6) + (s << 2);
    h4 e0 = *(const h4*)(eh  + o);
    h4 v1 = *(const h4*)(y1h + o);
    h4 v2 = *(const h4*)(y2h + o);
    float4 r;
    r.x = ((float)e0.x + (float)v1.x + (float)v2.x + acc.x * YSCALE_INV) * 0.25f;
    r.y = ((float)e0.y + (float)v1.y + (float)v2.y + acc.y * YSCALE_INV) * 0.25f;
    r.z = ((float)e0.z + (float)v1.z + (float)v2.z + acc.z * YSCALE_INV) * 0.25f;
    r.w = ((float)e0.w + (float)v1.w + (float)v2.w + acc.w * YSCALE_INV) * 0.25f;
    *(float4*)(out + o) = r;
}

// ===========================================================================
// Fallback atomic path (tiny ws only)
// ===========================================================================
__global__ void init_kernel(const float* __restrict__ user_t,
                            const float* __restrict__ item_t,
                            float* __restrict__ out,
                            float* __restrict__ bufA,
                            float* __restrict__ bufB) {
    int i = blockIdx.x * blockDim.x + threadIdx.x;
    const int total4 = N_NODES * EMB / 4;
    if (i >= total4) return;
    int fi   = i * 4;
    int node = fi >> 6;
    int off  = fi & 63;
    float4 v;
    if (node < N_USERS)
        v = *(const float4*)(user_t + (size_t)node * EMB + off);
    else
        v = *(const float4*)(item_t + (size_t)(node - N_USERS) * EMB + off);
    *(float4*)(out  + fi) = v;
    *(float4*)(bufA + fi) = v;
    *(float4*)(bufB + fi) = make_float4(0.f, 0.f, 0.f, 0.f);
}

__global__ void spmm_kernel(const int*   __restrict__ rows,
                            const int*   __restrict__ cols,
                            const float* __restrict__ vals,
                            const float* __restrict__ x,
                            float*       __restrict__ y) {
    int tid  = blockIdx.x * blockDim.x + threadIdx.x;
    int e    = tid >> 6;
    int lane = tid & 63;
    if (e >= NNZ) return;
    atomicAdd(&y[(size_t)rows[e] * EMB + lane], vals[e] * x[(size_t)cols[e] * EMB + lane]);
}

__global__ void acc_zero_kernel(float* __restrict__ out,
                                const float* __restrict__ src,
                                float* __restrict__ zbuf) {
    int i = blockIdx.x * blockDim.x + threadIdx.x;
    const int total4 = N_NODES * EMB / 4;
    if (i >= total4) return;
    int fi = i * 4;
    float4 o = *(float4*)(out + fi);
    float4 s = *(const float4*)(src + fi);
    o.x += s.x; o.y += s.y; o.z += s.z; o.w += s.w;
    *(float4*)(out  + fi) = o;
    *(float4*)(zbuf + fi) = make_float4(0.f, 0.f, 0.f, 0.f);
}

__global__ void final_kernel(float* __restrict__ out,
                             const float* __restrict__ src) {
    int i = blockIdx.x * blockDim.x + threadIdx.x;
    const int total4 = N_NODES * EMB / 4;
    if (i >= total4) return;
    int fi = i * 4;
    float4 o = *(float4*)(out + fi);
    float4 s = *(const float4*)(src + fi);
    o.x = (o.x + s.x) * 0.25f;
    o.y = (o.y + s.y) * 0.25f;
    o.z = (o.z + s.z) * 0.25f;
    o.w = (o.w + s.w) * 0.25f;
    *(float4*)(out + fi) = o;
}

// ===========================================================================
extern "C" void kernel_launch(void* const* d_in, const int* in_sizes, int n_in,
                              void* d_out, int out_size, void* d_ws, size_t ws_size,
                              hipStream_t stream) {
    const float* user_t = (const float*)d_in[0];
    const float* item_t = (const float*)d_in[1];
    const int*   rows   = (const int*)d_in[2];
    const int*   cols   = (const int*)d_in[3];
    const float* vals   = (const float*)d_in[4];
    float* out = (float*)d_out;

    const size_t embh_bytes = (size_t)N_NODES * EMB * 2;          // 38.4 MB
    const size_t embq_bytes = (size_t)N_NODES * EMB;              // 19.2 MB
    const size_t emb_bytes  = (size_t)N_NODES * EMB * 4;          // 76.8 MB
    const size_t pay_bytes  = (size_t)NBUCK * SEGCAP * 8;         // 34.8 MB
    const size_t edges_bytes = (size_t)NNZ * 8;                   // 32 MB
    const size_t small_bytes = (size_t)(N_NODES + 1) * 4
                             + (size_t)NBUCK * 16 * 4
                             + (size_t)(NBUCK + 1) * 4;
    const int total4    = N_NODES * EMB / 4;
    const int ew_blocks = (total4 + 255) / 256;

    const size_t need_h = pay_bytes + 3 * embh_bytes + 2 * embq_bytes
                        + edges_bytes + small_bytes;              // ~222 MB
    const int spmm_blocks = (int)(((size_t)N_NODES / 4 * 64 + 255) / 256); // 18750

    if (ws_size >= need_h) {
        // ---- fp16/fp8-gather tier ----
        char* p = (char*)d_ws;
        float2*       pay     = (float2*)p;       p += pay_bytes;
        _Float16*     eh      = (_Float16*)p;     p += embh_bytes;
        _Float16*     y1h     = (_Float16*)p;     p += embh_bytes;
        _Float16*     y2h     = (_Float16*)p;     p += embh_bytes;
        unsigned int* y1q     = (unsigned int*)p; p += embq_bytes;
        unsigned int* y2q     = (unsigned int*)p; p += embq_bytes;
        float2*       edges   = (float2*)p;       p += edges_bytes;
        int*          row_ptr = (int*)p;          p += (size_t)(N_NODES + 1) * 4;
        int*          bcnt    = (int*)p;          p += (size_t)NBUCK * 16 * 4;
        int*          bbase   = (int*)p;

        hipMemsetAsync(bcnt, 0, (size_t)NBUCK * 16 * 4, stream);
        bucket_agg_kernel<<<AGG_BLOCKS + EH_BLOCKS, AGG_THR, 0, stream>>>(
            rows, cols, vals, bcnt, pay, user_t, item_t, eh);
        bscan_kernel<<<1, 512, 0, stream>>>(bcnt, bbase, row_ptr);
        place_kernel<<<NBUCK, 1024, 0, stream>>>(bcnt, bbase, pay, row_ptr, edges);

        spmm_y1_kernel <<<spmm_blocks, 256, 0, stream>>>(row_ptr, edges, eh,  y1h, y1q);
        spmm_y2_kernel <<<spmm_blocks, 256, 0, stream>>>(row_ptr, edges, y1q, y2h, y2q);
        spmm_fin_kernel<<<spmm_blocks, 256, 0, stream>>>(row_ptr, edges, eh,
                                                         y1h, y2h, y2q, out);
    } else {
        // ---- tiny-ws fallback ----
        char* p = (char*)d_ws;
        float* bufA = (float*)p; p += emb_bytes;
        float* bufB = (float*)p;
        const int spmmA_blocks = (int)(((size_t)NNZ * 64 + 255) / 256);
        init_kernel<<<ew_blocks, 256, 0, stream>>>(user_t, item_t, out, bufA, bufB);
        spmm_kernel<<<spmmA_blocks, 256, 0, stream>>>(rows, cols, vals, bufA, bufB);
        acc_zero_kernel<<<ew_blocks, 256, 0, stream>>>(out, bufB, bufA);
        spmm_kernel<<<spmmA_blocks, 256, 0, stream>>>(rows, cols, vals, bufB, bufA);
        acc_zero_kernel<<<ew_blocks, 256, 0, stream>>>(out, bufA, bufB);
        spmm_kernel<<<spmmA_blocks, 256, 0, stream>>>(rows, cols, vals, bufA, bufB);
        final_kernel<<<ew_blocks, 256, 0, stream>>>(out, bufB);
    }
}